// Round 11
// baseline (209.003 us; speedup 1.0000x reference)
//
#include <hip/hip_runtime.h>

// Workspace float offsets
#define F_XM    0u          // bf16 xm[8][4096][256]      -> 4,194,304 f
#define F_XG    4194304u    // bf16 xg[8][2][4096][256]   -> 8,388,608 f
                            //   (later: y partials [ms][8][2][4096][128] bf16)
#define F_TH    12582912u   // bf16 theta[8][4096][128]   -> 2,097,152 f
#define F_PHIB  14680064u   // bf16 phi[8][1024][128]     ->   524,288 f
#define F_GB    15204352u   // bf16 g[8][256][1024]       -> 1,048,576 f
#define F_ML    16252928u   // float2 ml[ms=2][8][4096]   ->   131,072 f
// total 16,384,000 floats = 65.5 MB

typedef __attribute__((ext_vector_type(4))) float f32x4;
typedef __attribute__((ext_vector_type(8))) short bf16x8;

__device__ __forceinline__ unsigned short f2bf(float f) {
  union { unsigned int i; float f; } x; x.f = f;
  unsigned int r = x.i + 0x7fffu + ((x.i >> 16) & 1u);
  return (unsigned short)(r >> 16);
}
__device__ __forceinline__ unsigned int pk2(float a, float b) {
  return (unsigned int)f2bf(a) | ((unsigned int)f2bf(b) << 16);
}
__device__ __forceinline__ float bflo(unsigned int u) {
  union { unsigned int i; float f; } x; x.i = u << 16; return x.f;
}
__device__ __forceinline__ float bfhi(unsigned int u) {
  union { unsigned int i; float f; } x; x.i = u & 0xffff0000u; return x.f;
}
__device__ __forceinline__ void gload_lds16(const void* g, void* l) {
  __builtin_amdgcn_global_load_lds(
      (const __attribute__((address_space(1))) unsigned int*)g,
      (__attribute__((address_space(3))) unsigned int*)l, 16, 0, 0);
}

// ---------------------------------------------------------------------------
// Prep: x f32 [b][512][4096] -> bf16 xm[b][n][256] (mean over group pair) and
// xg[b][gr][n][256] (K-contiguous layouts for the MFMA GEMMs).
// ---------------------------------------------------------------------------
__global__ __launch_bounds__(256)
void k_prep(const float* __restrict__ x, float* __restrict__ ws) {
  const int nt = blockIdx.x, ct = blockIdx.y, b = blockIdx.z;
  const int n0 = nt * 256, c0 = ct * 64;
  const int tid = threadIdx.x;
  __shared__ uint4 ldsb[4096];               // 64 KB: f32 [64 c][1024B] swz
  char* lds = (char*)ldsb;
  {
    const int c = tid >> 2;
    const int nch = (tid & 3) * 64;
    const float* src = x + ((size_t)(b * 512 + c0 + c)) * 4096 + n0 + nch;
    char* row = lds + c * 1024;
    const int sw = (c & 7) << 4;
    const int bb = nch * 4;
#pragma unroll
    for (int k = 0; k < 16; ++k)
      *(uint4*)(row + ((bb + 16 * k) ^ sw)) = ((const uint4*)src)[k];
  }
  __syncthreads();
  {
    const int n = tid;
    unsigned int u0[16], u1[16], um[16];
#pragma unroll
    for (int jc = 0; jc < 4; ++jc) {
      float v[16];
#pragma unroll
      for (int cc = 0; cc < 16; ++cc) {
        const int c = 16 * jc + cc;
        v[cc] = *(const float*)(lds + c * 1024 + ((n * 4) ^ ((c & 7) << 4)));
      }
#pragma unroll
      for (int s = 0; s < 4; ++s) {
        u0[4 * jc + s] = pk2(v[4 * s], v[4 * s + 2]);
        u1[4 * jc + s] = pk2(v[4 * s + 1], v[4 * s + 3]);
        um[4 * jc + s] = pk2(0.5f * (v[4 * s] + v[4 * s + 1]),
                             0.5f * (v[4 * s + 2] + v[4 * s + 3]));
      }
    }
    unsigned short* xm = (unsigned short*)(ws + F_XM);
    unsigned short* xg = (unsigned short*)(ws + F_XG);
    uint4* d0 = (uint4*)(xg + (((size_t)(b * 2 + 0) * 4096) + n0 + n) * 256 + (c0 >> 1));
    uint4* d1 = (uint4*)(xg + (((size_t)(b * 2 + 1) * 4096) + n0 + n) * 256 + (c0 >> 1));
    uint4* dm = (uint4*)(xm + ((size_t)(b * 4096) + n0 + n) * 256 + (c0 >> 1));
#pragma unroll
    for (int s = 0; s < 4; ++s) {
      d0[s] = make_uint4(u0[4 * s], u0[4 * s + 1], u0[4 * s + 2], u0[4 * s + 3]);
      d1[s] = make_uint4(u1[4 * s], u1[4 * s + 1], u1[4 * s + 2], u1[4 * s + 3]);
      dm[s] = make_uint4(um[4 * s], um[4 * s + 1], um[4 * s + 2], um[4 * s + 3]);
    }
  }
}

// ---------------------------------------------------------------------------
// theta & phi projections from xm (K=256). Out tile 128 o x 128 n, 4 waves.
// ot=0: theta[b][n][o] bf16 (LDS transpose). ot=1: pooled phiB[b][m][o] bf16.
// ---------------------------------------------------------------------------
__global__ __launch_bounds__(256)
void k_proj_mfma(const float* __restrict__ tw, const float* __restrict__ tb,
                 const float* __restrict__ pw, const float* __restrict__ pb,
                 float* __restrict__ ws) {
  const int nt = blockIdx.x, ot = blockIdx.y, b = blockIdx.z;
  const int n0 = nt * 128;
  const int tid = threadIdx.x;
  const int w = tid >> 6, lane = tid & 63, q = lane >> 4, col = lane & 15;
  const float* W = ot ? pw : tw;
  const float* bias = ot ? pb : tb;
  const unsigned short* xm = (const unsigned short*)(ws + F_XM);

  __shared__ uint4 ldsb[4096];               // 64 KB
  char* Ws = (char*)ldsb;                    // [128 o][128B] swz
  char* Xs = (char*)ldsb + 16384;            // [128 n][128B] swz

  f32x4 acc[2][8];
#pragma unroll
  for (int h = 0; h < 2; ++h)
#pragma unroll
    for (int j = 0; j < 8; ++j) acc[h][j] = (f32x4){0.f, 0.f, 0.f, 0.f};

  const int ro = tid >> 1, haf = tid & 1;
  for (int ks = 0; ks < 4; ++ks) {
    __syncthreads();
    {
      const float* src = W + (size_t)ro * 256 + ks * 64 + haf * 32;
      char* row = Ws + ro * 128;
      const int sw = (ro & 7) << 4;
#pragma unroll
      for (int jj = 0; jj < 4; ++jj) {
        float4 a = ((const float4*)src)[2 * jj];
        float4 c4 = ((const float4*)src)[2 * jj + 1];
        uint4 pk;
        pk.x = pk2(a.x, a.y);  pk.y = pk2(a.z, a.w);
        pk.z = pk2(c4.x, c4.y); pk.w = pk2(c4.z, c4.w);
        *(uint4*)(row + ((haf * 64 + 16 * jj) ^ sw)) = pk;
      }
    }
    {
      const unsigned short* src = xm + ((size_t)(b * 4096) + n0 + ro) * 256 + ks * 64 + haf * 32;
      char* row = Xs + ro * 128;
      const int sw = (ro & 7) << 4;
#pragma unroll
      for (int jj = 0; jj < 4; ++jj)
        *(uint4*)(row + ((haf * 64 + 16 * jj) ^ sw)) = ((const uint4*)src)[jj];
    }
    __syncthreads();
#pragma unroll
    for (int c = 0; c < 2; ++c) {
      bf16x8 af[2], bfr[8];
#pragma unroll
      for (int h = 0; h < 2; ++h) {
        const int r = 32 * w + 16 * h + col;
        af[h] = *(const bf16x8*)(Ws + r * 128 + ((64 * c + 16 * q) ^ ((r & 7) << 4)));
      }
#pragma unroll
      for (int j = 0; j < 8; ++j) {
        const int r = 16 * j + col;
        bfr[j] = *(const bf16x8*)(Xs + r * 128 + ((64 * c + 16 * q) ^ ((r & 7) << 4)));
      }
#pragma unroll
      for (int h = 0; h < 2; ++h)
#pragma unroll
        for (int j = 0; j < 8; ++j)
          acc[h][j] = __builtin_amdgcn_mfma_f32_16x16x32_bf16(af[h], bfr[j], acc[h][j], 0, 0, 0);
    }
  }

  float bs[2][4];
#pragma unroll
  for (int h = 0; h < 2; ++h) {
    const int o0 = 32 * w + 16 * h + 4 * q;
#pragma unroll
    for (int r = 0; r < 4; ++r) bs[h][r] = bias[o0 + r];
  }

  if (ot == 0) {
    char* trb = (char*)ldsb + 32768;         // [128 n][256B] swz, fresh region
#pragma unroll
    for (int h = 0; h < 2; ++h) {
      const int o0 = 32 * w + 16 * h + 4 * q;
#pragma unroll
      for (int j = 0; j < 8; ++j) {
        const int n = 16 * j + col;
        uint2 pkk = make_uint2(pk2(acc[h][j][0] + bs[h][0], acc[h][j][1] + bs[h][1]),
                               pk2(acc[h][j][2] + bs[h][2], acc[h][j][3] + bs[h][3]));
        *(uint2*)(trb + n * 256 + ((2 * o0) ^ ((n & 7) << 4))) = pkk;
      }
    }
    __syncthreads();
    {
      const int n = tid >> 1, h2 = tid & 1;
      unsigned short* dst = (unsigned short*)(ws + F_TH) + ((size_t)(b * 4096) + n0 + n) * 128 + h2 * 64;
      const char* row = trb + n * 256;
      const int sw = (n & 7) << 4;
#pragma unroll
      for (int k = 0; k < 8; ++k)
        ((uint4*)dst)[k] = *(const uint4*)(row + ((128 * h2 + 16 * k) ^ sw));
    }
  } else {
    const int mb = (nt >> 3) * 256 + (nt & 7) * 32;
    unsigned short* phiB = (unsigned short*)(ws + F_PHIB);
#pragma unroll
    for (int h = 0; h < 2; ++h) {
      const int o0 = 32 * w + 16 * h + 4 * q;
#pragma unroll
      for (int jj = 0; jj < 4; ++jj) {
        const int j = (jj >> 1) * 4 + (jj & 1);   // {0,1,4,5}
        f32x4 pm;
#pragma unroll
        for (int r = 0; r < 4; ++r)
          pm[r] = fmaxf(acc[h][j][r], acc[h][j + 2][r]);
#pragma unroll
        for (int r = 0; r < 4; ++r)
          pm[r] = fmaxf(pm[r], __shfl_xor(pm[r], 1));
        if ((col & 1) == 0) {
          const int vp = 8 * (j & 1) + (col >> 1);
          const int m = mb + 16 * (j >> 2) + vp;
          uint2 pkk = make_uint2(pk2(pm[0] + bs[h][0], pm[1] + bs[h][1]),
                                 pk2(pm[2] + bs[h][2], pm[3] + bs[h][3]));
          *(uint2*)(phiB + ((size_t)(b * 1024) + m) * 128 + o0) = pkk;
        }
      }
    }
  }
}

// ---------------------------------------------------------------------------
// g projection from xg (per group, K=256), fused pool -> gB[b][d=2o+gr][m].
// ---------------------------------------------------------------------------
__global__ __launch_bounds__(256)
void k_g_mfma(const float* __restrict__ gw, const float* __restrict__ gb,
              float* __restrict__ ws) {
  const int nt = blockIdx.x, gr = blockIdx.y, b = blockIdx.z;
  const int n0 = nt * 128;
  const int tid = threadIdx.x;
  const int w = tid >> 6, lane = tid & 63, q = lane >> 4, col = lane & 15;
  const unsigned short* xg = (const unsigned short*)(ws + F_XG);

  __shared__ uint4 ldsb[4096];
  char* Ws = (char*)ldsb;
  char* Xs = (char*)ldsb + 16384;

  f32x4 acc[2][8];
#pragma unroll
  for (int h = 0; h < 2; ++h)
#pragma unroll
    for (int j = 0; j < 8; ++j) acc[h][j] = (f32x4){0.f, 0.f, 0.f, 0.f};

  const int ro = tid >> 1, haf = tid & 1;
  for (int ks = 0; ks < 4; ++ks) {
    __syncthreads();
    {
      const float* src = gw + (size_t)ro * 256 + ks * 64 + haf * 32;
      char* row = Ws + ro * 128;
      const int sw = (ro & 7) << 4;
#pragma unroll
      for (int jj = 0; jj < 4; ++jj) {
        float4 a = ((const float4*)src)[2 * jj];
        float4 c4 = ((const float4*)src)[2 * jj + 1];
        uint4 pk;
        pk.x = pk2(a.x, a.y);  pk.y = pk2(a.z, a.w);
        pk.z = pk2(c4.x, c4.y); pk.w = pk2(c4.z, c4.w);
        *(uint4*)(row + ((haf * 64 + 16 * jj) ^ sw)) = pk;
      }
    }
    {
      const unsigned short* src = xg + (((size_t)(b * 2 + gr)) * 4096 + n0 + ro) * 256 + ks * 64 + haf * 32;
      char* row = Xs + ro * 128;
      const int sw = (ro & 7) << 4;
#pragma unroll
      for (int jj = 0; jj < 4; ++jj)
        *(uint4*)(row + ((haf * 64 + 16 * jj) ^ sw)) = ((const uint4*)src)[jj];
    }
    __syncthreads();
#pragma unroll
    for (int c = 0; c < 2; ++c) {
      bf16x8 af[2], bfr[8];
#pragma unroll
      for (int h = 0; h < 2; ++h) {
        const int r = 32 * w + 16 * h + col;
        af[h] = *(const bf16x8*)(Ws + r * 128 + ((64 * c + 16 * q) ^ ((r & 7) << 4)));
      }
#pragma unroll
      for (int j = 0; j < 8; ++j) {
        const int r = 16 * j + col;
        bfr[j] = *(const bf16x8*)(Xs + r * 128 + ((64 * c + 16 * q) ^ ((r & 7) << 4)));
      }
#pragma unroll
      for (int h = 0; h < 2; ++h)
#pragma unroll
        for (int j = 0; j < 8; ++j)
          acc[h][j] = __builtin_amdgcn_mfma_f32_16x16x32_bf16(af[h], bfr[j], acc[h][j], 0, 0, 0);
    }
  }

  const int mb = (nt >> 3) * 256 + (nt & 7) * 32;
  char* pt = (char*)ldsb + 32768;            // [128 o][80B], fresh region
#pragma unroll
  for (int h = 0; h < 2; ++h) {
    const int o0 = 32 * w + 16 * h + 4 * q;
#pragma unroll
    for (int jj = 0; jj < 4; ++jj) {
      const int j = (jj >> 1) * 4 + (jj & 1);
      f32x4 pm;
#pragma unroll
      for (int r = 0; r < 4; ++r)
        pm[r] = fmaxf(acc[h][j][r], acc[h][j + 2][r]);
#pragma unroll
      for (int r = 0; r < 4; ++r)
        pm[r] = fmaxf(pm[r], __shfl_xor(pm[r], 1));
      if ((col & 1) == 0) {
        const int ml = 16 * (j >> 2) + 8 * (j & 1) + (col >> 1);
#pragma unroll
        for (int r = 0; r < 4; ++r)
          *(unsigned short*)(pt + (o0 + r) * 80 + ml * 2) = f2bf(pm[r] + gb[o0 + r]);
      }
    }
  }
  __syncthreads();
  if (tid < 128) {
    const int o = tid;
    const char* row = pt + o * 80;
    unsigned short* dst = (unsigned short*)(ws + F_GB) + ((size_t)(b * 256) + 2 * o + gr) * 1024 + mb;
#pragma unroll
    for (int k = 0; k < 4; ++k)
      ((uint4*)dst)[k] = *(const uint4*)(row + 16 * k);
  }
}

// ---------------------------------------------------------------------------
// MFMA flash attention v8: m-split (2 partials/row, combined in k_final),
// 8 waves = 4 row-groups x 2 d-halves (each wave 32 n-rows, half the V reads;
// twin waves write byte-identical P duplicates). K single-buffer 8KB with
// post-QK barrier; V pair-dbuf 2x32KB (verified layout); P 8KB.
// LDS 80KB exactly -> 2 blocks/CU, 4 waves/SIMD.
// ---------------------------------------------------------------------------
#define NITH 16
__global__ __launch_bounds__(512, 4)
void k_attn_mfma(float* __restrict__ ws) {
  const int b = blockIdx.x;          // 8 batches -> 8 XCDs (round-robin)
  const int n0 = blockIdx.y * 128;
  const int ms = blockIdx.z;         // m-half
  const int tid = threadIdx.x;
  const int w = tid >> 6;
  const int lane = tid & 63;
  const int q = lane >> 4;
  const int col = lane & 15;
  const int g = w & 3;               // row-group (rows 32g..32g+31)
  const int dh = w >> 2;             // d-half (d 128*dh..+127)
  const int ksw = (col & 7) << 4;
  const int psw = (col & 3) << 4;

  __shared__ char lds[81920];
  // kt: 8KB @0 (K tile [32 m][256B] swz (m&7)<<4), single-buffered
  // vbuf[2]: 2x32KB @8192 (V^T pair-tile [256 d][128B] swz (d&7)<<4)
  // P: 8KB @73728  [4 g][2 cg][16 col][64B] swz (col&3)<<4
  char* kt = lds;
  char* pbase = lds + 73728 + g * 2048;

  const unsigned short* thetaB = (const unsigned short*)(ws + F_TH);
  const char* phiBb = (const char*)((const unsigned short*)(ws + F_PHIB) + (size_t)b * 1024 * 128);
  const char* gBb   = (const char*)((const unsigned short*)(ws + F_GB) + (size_t)b * 256 * 1024);
  unsigned short* yBp = (unsigned short*)(ws + F_XG) + (size_t)ms * 8388608;
  float2* mlp = (float2*)(ws + F_ML) + ((size_t)(ms * 8 + b)) * 4096;

  // staging lane geometry (pre-swizzled global source, linear LDS dest)
  const int kr0 = lane >> 4;               // K: row within 4-row chunk
  const int kso = (lane & 15) * 16;
  const int vr0 = lane >> 3;               // V: row within 8-row chunk
  const int vso = (lane & 7) * 16;
  const int mbase = ms * 512;              // this block's m range start

  // Q fragments: 2 col-groups of 16 rows each
  bf16x8 qf[2][4];
#pragma unroll
  for (int cg = 0; cg < 2; ++cg) {
    const unsigned short* qp = thetaB +
        ((size_t)(b * 4096 + n0 + 32 * g + 16 * cg + col)) * 128 + 8 * q;
#pragma unroll
    for (int c = 0; c < 4; ++c) qf[cg][c] = *(const bf16x8*)(qp + 32 * c);
  }

  f32x4 ot[2][8];
#pragma unroll
  for (int cg = 0; cg < 2; ++cg)
#pragma unroll
    for (int t = 0; t < 8; ++t) ot[cg][t] = (f32x4){0.f, 0.f, 0.f, 0.f};
  float mrun[2] = {-1e30f, -1e30f}, lsum[2] = {0.f, 0.f};

  // prologue: K it0 (wave w -> chunk w) + V pair0 (wave w -> chunks 4w..4w+3)
  {
    const int r = 4 * w + kr0;
    gload_lds16(phiBb + (size_t)(mbase + r) * 256 + (kso ^ ((r & 7) << 4)), kt + w * 1024);
#pragma unroll
    for (int j = 0; j < 4; ++j) {
      const int c = 4 * w + j;
      const int d = 8 * c + vr0;
      gload_lds16(gBb + (size_t)d * 2048 + (size_t)mbase * 2 + (vso ^ ((d & 7) << 4)),
                  lds + 8192 + c * 1024);
    }
  }
  __syncthreads();

  for (int it = 0; it < NITH; ++it) {
    char* vtc = lds + 8192 + ((it >> 1) & 1) * 32768;
    const int par = it & 1;

    // S^T = K . Q^T : kf shared by both col-groups
    f32x4 st[2][2];
#pragma unroll
    for (int cg = 0; cg < 2; ++cg)
#pragma unroll
      for (int s = 0; s < 2; ++s) st[cg][s] = (f32x4){0.f, 0.f, 0.f, 0.f};
    __builtin_amdgcn_s_setprio(1);
#pragma unroll
    for (int c = 0; c < 4; ++c)
#pragma unroll
      for (int s = 0; s < 2; ++s) {
        const bf16x8 kf = *(const bf16x8*)(kt + (16 * s + col) * 256 +
                                           ((64 * c + 16 * q) ^ ksw));
        st[0][s] = __builtin_amdgcn_mfma_f32_16x16x32_bf16(kf, qf[0][c], st[0][s], 0, 0, 0);
        st[1][s] = __builtin_amdgcn_mfma_f32_16x16x32_bf16(kf, qf[1][c], st[1][s], 0, 0, 0);
      }
    __builtin_amdgcn_s_setprio(0);
    __syncthreads();                 // #1: all QK reads of kt done block-wide

    // issue next K tile into the (now-free) single K buffer
    if (it + 1 < NITH) {
      const int r = 4 * w + kr0;
      gload_lds16(phiBb + (size_t)(mbase + (it + 1) * 32 + r) * 256 + (kso ^ ((r & 7) << 4)),
                  kt + w * 1024);
    }
    // issue next V pair into the other V buffer
    if (par == 0 && (it >> 1) + 1 < 8) {
      const size_t vm = (size_t)(mbase + ((it >> 1) + 1) * 64) * 2;
#pragma unroll
      for (int j = 0; j < 4; ++j) {
        const int c = 4 * w + j;
        const int d = 8 * c + vr0;
        gload_lds16(gBb + (size_t)d * 2048 + vm + (vso ^ ((d & 7) << 4)),
                    lds + 8192 + (((it >> 1) & 1) ^ 1) * 32768 + c * 1024);
      }
    }

    // online softmax (defer-max, threshold 8) + P write, per col-group
    bf16x8 pf[2];
#pragma unroll
    for (int cg = 0; cg < 2; ++cg) {
      float pmax = -1e30f;
#pragma unroll
      for (int s = 0; s < 2; ++s)
#pragma unroll
        for (int r = 0; r < 4; ++r) pmax = fmaxf(pmax, st[cg][s][r]);
      pmax = fmaxf(pmax, __shfl_xor(pmax, 16));
      pmax = fmaxf(pmax, __shfl_xor(pmax, 32));
      if (!__all(pmax - mrun[cg] <= 8.f)) {
        const float mnew = fmaxf(mrun[cg], pmax);
        const float scl = __expf(mrun[cg] - mnew);
        mrun[cg] = mnew;
        lsum[cg] *= scl;
#pragma unroll
        for (int t = 0; t < 8; ++t) {
          ot[cg][t][0] *= scl; ot[cg][t][1] *= scl;
          ot[cg][t][2] *= scl; ot[cg][t][3] *= scl;
        }
      }
      float rsum = 0.f;
#pragma unroll
      for (int s = 0; s < 2; ++s)
#pragma unroll
        for (int r = 0; r < 4; ++r) {
          st[cg][s][r] = __expf(st[cg][s][r] - mrun[cg]);
          rsum += st[cg][s][r];
        }
      rsum += __shfl_xor(rsum, 16);
      rsum += __shfl_xor(rsum, 32);
      lsum[cg] += rsum;

      // both d-half twins write byte-identical values (benign duplicates)
      char* prow = pbase + cg * 1024 + col * 64;
#pragma unroll
      for (int s = 0; s < 2; ++s)
#pragma unroll
        for (int hp = 0; hp < 2; ++hp)
          *(unsigned int*)(prow + ((32 * s + 8 * q + 4 * hp) ^ psw)) =
              pk2(st[cg][s][2 * hp], st[cg][s][2 * hp + 1]);
      pf[cg] = *(const bf16x8*)(prow + ((16 * q) ^ psw));
    }

    // O^T += V^T . P^T  (only this wave's d-half; vf shared across cg)
    __builtin_amdgcn_s_setprio(1);
#pragma unroll
    for (int t = 0; t < 8; ++t) {
      const int d = 128 * dh + 16 * t + col;
      const bf16x8 vf = *(const bf16x8*)(vtc + d * 128 +
                                         ((64 * par + 16 * q) ^ ((d & 7) << 4)));
      ot[0][t] = __builtin_amdgcn_mfma_f32_16x16x32_bf16(vf, pf[0], ot[0][t], 0, 0, 0);
      ot[1][t] = __builtin_amdgcn_mfma_f32_16x16x32_bf16(vf, pf[1], ot[1][t], 0, 0, 0);
    }
    __builtin_amdgcn_s_setprio(0);

    __syncthreads();                 // #2: staged tiles complete, buffers free
  }

  // store per-row (m, l) — one d-half writes
  if (dh == 0 && q == 0) {
#pragma unroll
    for (int cg = 0; cg < 2; ++cg)
      mlp[n0 + 32 * g + 16 * cg + col] = make_float2(mrun[cg], lsum[cg]);
  }

  // epilogue: UNNORMALIZED partial y_p[b][gr][n][i] bf16 via LDS transpose.
  // d = 128*dh + 16t + 4q + r -> gr = r&1, i = 64*dh + 8t + 2q + (r>>1)
  char* yt = lds;                    // [256 rows (gr*128+nl)][256B] swz
#pragma unroll
  for (int cg = 0; cg < 2; ++cg) {
    const int nl = 32 * g + 16 * cg + col;
    const int swn = (nl & 7) << 4;
#pragma unroll
    for (int t = 0; t < 8; ++t) {
      const unsigned int w0 = pk2(ot[cg][t][0], ot[cg][t][2]);
      const unsigned int w1 = pk2(ot[cg][t][1], ot[cg][t][3]);
      const int bo = 128 * dh + 16 * t + 4 * q;
      *(unsigned int*)(yt + nl * 256 + (bo ^ swn)) = w0;
      *(unsigned int*)(yt + (128 + nl) * 256 + (bo ^ swn)) = w1;
    }
  }
  __syncthreads();
  {
    const int row = tid >> 1, h2 = tid & 1;
    const int gr = row >> 7, n = row & 127;
    unsigned short* dst = yBp + (((size_t)(b * 2 + gr)) * 4096 + n0 + n) * 128 + h2 * 64;
    const char* srow = yt + row * 256;
    const int sw = (n & 7) << 4;
#pragma unroll
    for (int k = 0; k < 8; ++k)
      ((uint4*)dst)[k] = *(const uint4*)(srow + ((128 * h2 + 16 * k) ^ sw));
  }
}

// ---------------------------------------------------------------------------
// Final W conv (MFMA, K=128 per group) + bias + residual.
// B-staging COMBINES the two attention partials: y = c0*O0 + c1*O1 with
// c_p = e^{m_p-M}/(e^{m0-M} l0 + e^{m1-M} l1)  (exact, f32).
// ---------------------------------------------------------------------------
__global__ __launch_bounds__(256)
void k_final_mfma(const float* __restrict__ x,
                  const float* __restrict__ Ww, const float* __restrict__ Wb,
                  const float* __restrict__ ws, float* __restrict__ out) {
  const int nt = blockIdx.x, gq = blockIdx.y, b = blockIdx.z;
  const int gr = gq & 1, ob = (gq >> 1) * 128;
  const int n0 = nt * 128;
  const int tid = threadIdx.x;
  const int w = tid >> 6, lane = tid & 63, q = lane >> 4, col = lane & 15;
  const unsigned short* yb = (const unsigned short*)(ws + F_XG);

  __shared__ uint4 ldsb[4096];
  char* As = (char*)ldsb;
  char* Bs = (char*)ldsb + 16384;

  f32x4 acc[2][8];
#pragma unroll
  for (int h = 0; h < 2; ++h)
#pragma unroll
    for (int j = 0; j < 8; ++j) acc[h][j] = (f32x4){0.f, 0.f, 0.f, 0.f};

  const int ro = tid >> 1, haf = tid & 1;

  // per-row combine coefficients (row = n0 + ro)
  const float2 ml0 = *((const float2*)(ws + F_ML) + (size_t)b * 4096 + n0 + ro);
  const float2 ml1 = *((const float2*)(ws + F_ML) + (size_t)(8 + b) * 4096 + n0 + ro);
  const float M = fmaxf(ml0.x, ml1.x);
  const float e0 = __expf(ml0.x - M), e1 = __expf(ml1.x - M);
  const float rden = 1.0f / (e0 * ml0.y + e1 * ml1.y);
  const float c0 = e0 * rden, c1 = e1 * rden;

  for (int ks = 0; ks < 2; ++ks) {
    __syncthreads();
    {
      const float* src = Ww + (size_t)(ob + ro) * 128 + ks * 64 + haf * 32;
      char* row = As + ro * 128;
      const int sw = (ro & 7) << 4;
#pragma unroll
      for (int jj = 0; jj < 4; ++jj) {
        float4 a = ((const float4*)src)[2 * jj];
        float4 c4 = ((const float4*)src)[2 * jj + 1];
        uint4 pk;
        pk.x = pk2(a.x, a.y);  pk.y = pk2(a.z, a.w);
        pk.z = pk2(c4.x, c4.y); pk.w = pk2(c4.z, c4.w);
        *(uint4*)(row + ((haf * 64 + 16 * jj) ^ sw)) = pk;
      }
    }
    {
      const size_t yoff = (((size_t)(b * 2 + gr)) * 4096 + n0 + ro) * 128 + ks * 64 + haf * 32;
      const unsigned short* y0 = yb + yoff;
      const unsigned short* y1 = yb + 8388608 + yoff;
      char* row = Bs + ro * 128;
      const int sw = (ro & 7) << 4;
#pragma unroll
      for (int jj = 0; jj < 4; ++jj) {
        const uint4 ua = ((const uint4*)y0)[jj];
        const uint4 ub = ((const uint4*)y1)[jj];
        uint4 o;
        o.x = pk2(c0 * bflo(ua.x) + c1 * bflo(ub.x), c0 * bfhi(ua.x) + c1 * bfhi(ub.x));
        o.y = pk2(c0 * bflo(ua.y) + c1 * bflo(ub.y), c0 * bfhi(ua.y) + c1 * bfhi(ub.y));
        o.z = pk2(c0 * bflo(ua.z) + c1 * bflo(ub.z), c0 * bfhi(ua.z) + c1 * bfhi(ub.z));
        o.w = pk2(c0 * bflo(ua.w) + c1 * bflo(ub.w), c0 * bfhi(ua.w) + c1 * bfhi(ub.w));
        *(uint4*)(row + ((haf * 64 + 16 * jj) ^ sw)) = o;
      }
    }
    __syncthreads();
#pragma unroll
    for (int c = 0; c < 2; ++c) {
      bf16x8 af[2], bfr[8];
#pragma unroll
      for (int h = 0; h < 2; ++h) {
        const int r = 32 * w + 16 * h + col;
        af[h] = *(const bf16x8*)(As + r * 128 + ((64 * c + 16 * q) ^ ((r & 7) << 4)));
      }
#pragma unroll
      for (int j = 0; j < 8; ++j) {
        const int r = 16 * j + col;
        bfr[j] = *(const bf16x8*)(Bs + r * 128 + ((64 * c + 16 * q) ^ ((r & 7) << 4)));
      }
#pragma unroll
      for (int h = 0; h < 2; ++h)
#pragma unroll
        for (int j = 0; j < 8; ++j)
          acc[h][j] = __builtin_amdgcn_mfma_f32_16x16x32_bf16(af[h], bfr[j], acc[h][j], 0, 0, 0);
    }
  }

  __syncthreads();                           // reuse whole LDS: f32 [128 o][512B]
  char* ft = (char*)ldsb;
#pragma unroll
  for (int h = 0; h < 2; ++h) {
    const int o0 = 32 * w + 16 * h + 4 * q;
#pragma unroll
    for (int j = 0; j < 8; ++j) {
      const int n = 16 * j + col;
#pragma unroll
      for (int r = 0; r < 4; ++r)
        *(float*)(ft + (o0 + r) * 512 + ((n * 4) ^ (((o0 + r) & 7) << 4))) = acc[h][j][r];
    }
  }
  __syncthreads();
  {
    const int o = tid >> 1, h2 = tid & 1;
    const float bsv = Wb[ob + o];
    const int ch = 2 * (ob + o) + gr;
    const size_t base = ((size_t)(b * 512 + ch)) * 4096 + n0 + h2 * 64;
    const char* row = ft + o * 512;
    const int sw = (o & 7) << 4;
#pragma unroll
    for (int k = 0; k < 16; ++k) {
      f32x4 v = *(const f32x4*)(row + ((256 * h2 + 16 * k) ^ sw));
      float4 xv = ((const float4*)(x + base))[k];
      ((float4*)(out + base))[k] = make_float4(v[0] + bsv + xv.x, v[1] + bsv + xv.y,
                                               v[2] + bsv + xv.z, v[3] + bsv + xv.w);
    }
  }
}

extern "C" void kernel_launch(void* const* d_in, const int* in_sizes, int n_in,
                              void* d_out, int out_size, void* d_ws, size_t ws_size,
                              hipStream_t stream) {
  const float* x  = (const float*)d_in[0];
  const float* gw = (const float*)d_in[1];
  const float* gb = (const float*)d_in[2];
  const float* tw = (const float*)d_in[3];
  const float* tb = (const float*)d_in[4];
  const float* pw = (const float*)d_in[5];
  const float* pb = (const float*)d_in[6];
  const float* Ww = (const float*)d_in[7];
  const float* Wb = (const float*)d_in[8];
  float* out = (float*)d_out;
  float* ws  = (float*)d_ws;

  k_prep<<<dim3(16, 8, 8), 256, 0, stream>>>(x, ws);
  k_proj_mfma<<<dim3(32, 2, 8), 256, 0, stream>>>(tw, tb, pw, pb, ws);
  k_g_mfma<<<dim3(32, 2, 8), 256, 0, stream>>>(gw, gb, ws);
  k_attn_mfma<<<dim3(8, 32, 2), 512, 0, stream>>>(ws);
  k_final_mfma<<<dim3(32, 4, 8), 256, 0, stream>>>(x, Ww, Wb, ws, out);
}

// Round 12
// 172.335 us; speedup vs baseline: 1.2128x; 1.2128x over previous
//
#include <hip/hip_runtime.h>

// Workspace float offsets
#define F_XM    0u          // bf16 xm[8][4096][256]      -> 4,194,304 f
#define F_XG    4194304u    // bf16 xg[8][2][4096][256]   -> 8,388,608 f
#define F_Y     4194304u    // bf16 y[8][2][4096][128] aliases xg (dead after k_g)
#define F_TH    12582912u   // bf16 theta[8][4096][128]   -> 2,097,152 f
#define F_PHIB  14680064u   // bf16 phi[8][1024][128]     ->   524,288 f
#define F_GB    15204352u   // bf16 g[8][256][1024]       -> 1,048,576 f
// total 16,252,928 floats = 65.0 MB

typedef __attribute__((ext_vector_type(4))) float f32x4;
typedef __attribute__((ext_vector_type(8))) short bf16x8;

__device__ __forceinline__ unsigned short f2bf(float f) {
  union { unsigned int i; float f; } x; x.f = f;
  unsigned int r = x.i + 0x7fffu + ((x.i >> 16) & 1u);
  return (unsigned short)(r >> 16);
}
__device__ __forceinline__ unsigned int pk2(float a, float b) {
  return (unsigned int)f2bf(a) | ((unsigned int)f2bf(b) << 16);
}
__device__ __forceinline__ void gload_lds16(const void* g, void* l) {
  __builtin_amdgcn_global_load_lds(
      (const __attribute__((address_space(1))) unsigned int*)g,
      (__attribute__((address_space(3))) unsigned int*)l, 16, 0, 0);
}

// ---------------------------------------------------------------------------
// Prep: x f32 [b][512][4096] -> bf16 xm[b][n][256] (mean over group pair) and
// xg[b][gr][n][256] (K-contiguous layouts for the MFMA GEMMs).
// ---------------------------------------------------------------------------
__global__ __launch_bounds__(256)
void k_prep(const float* __restrict__ x, float* __restrict__ ws) {
  const int nt = blockIdx.x, ct = blockIdx.y, b = blockIdx.z;
  const int n0 = nt * 256, c0 = ct * 64;
  const int tid = threadIdx.x;
  __shared__ uint4 ldsb[4096];               // 64 KB: f32 [64 c][1024B] swz
  char* lds = (char*)ldsb;
  {
    const int c = tid >> 2;
    const int nch = (tid & 3) * 64;
    const float* src = x + ((size_t)(b * 512 + c0 + c)) * 4096 + n0 + nch;
    char* row = lds + c * 1024;
    const int sw = (c & 7) << 4;
    const int bb = nch * 4;
#pragma unroll
    for (int k = 0; k < 16; ++k)
      *(uint4*)(row + ((bb + 16 * k) ^ sw)) = ((const uint4*)src)[k];
  }
  __syncthreads();
  {
    const int n = tid;
    unsigned int u0[16], u1[16], um[16];
#pragma unroll
    for (int jc = 0; jc < 4; ++jc) {
      float v[16];
#pragma unroll
      for (int cc = 0; cc < 16; ++cc) {
        const int c = 16 * jc + cc;
        v[cc] = *(const float*)(lds + c * 1024 + ((n * 4) ^ ((c & 7) << 4)));
      }
#pragma unroll
      for (int s = 0; s < 4; ++s) {
        u0[4 * jc + s] = pk2(v[4 * s], v[4 * s + 2]);
        u1[4 * jc + s] = pk2(v[4 * s + 1], v[4 * s + 3]);
        um[4 * jc + s] = pk2(0.5f * (v[4 * s] + v[4 * s + 1]),
                             0.5f * (v[4 * s + 2] + v[4 * s + 3]));
      }
    }
    unsigned short* xm = (unsigned short*)(ws + F_XM);
    unsigned short* xg = (unsigned short*)(ws + F_XG);
    uint4* d0 = (uint4*)(xg + (((size_t)(b * 2 + 0) * 4096) + n0 + n) * 256 + (c0 >> 1));
    uint4* d1 = (uint4*)(xg + (((size_t)(b * 2 + 1) * 4096) + n0 + n) * 256 + (c0 >> 1));
    uint4* dm = (uint4*)(xm + ((size_t)(b * 4096) + n0 + n) * 256 + (c0 >> 1));
#pragma unroll
    for (int s = 0; s < 4; ++s) {
      d0[s] = make_uint4(u0[4 * s], u0[4 * s + 1], u0[4 * s + 2], u0[4 * s + 3]);
      d1[s] = make_uint4(u1[4 * s], u1[4 * s + 1], u1[4 * s + 2], u1[4 * s + 3]);
      dm[s] = make_uint4(um[4 * s], um[4 * s + 1], um[4 * s + 2], um[4 * s + 3]);
    }
  }
}

// ---------------------------------------------------------------------------
// theta & phi projections from xm (K=256). Out tile 128 o x 128 n, 4 waves.
// ot=0: theta[b][n][o] bf16 (LDS transpose). ot=1: pooled phiB[b][m][o] bf16.
// ---------------------------------------------------------------------------
__global__ __launch_bounds__(256)
void k_proj_mfma(const float* __restrict__ tw, const float* __restrict__ tb,
                 const float* __restrict__ pw, const float* __restrict__ pb,
                 float* __restrict__ ws) {
  const int nt = blockIdx.x, ot = blockIdx.y, b = blockIdx.z;
  const int n0 = nt * 128;
  const int tid = threadIdx.x;
  const int w = tid >> 6, lane = tid & 63, q = lane >> 4, col = lane & 15;
  const float* W = ot ? pw : tw;
  const float* bias = ot ? pb : tb;
  const unsigned short* xm = (const unsigned short*)(ws + F_XM);

  __shared__ uint4 ldsb[4096];               // 64 KB
  char* Ws = (char*)ldsb;                    // [128 o][128B] swz
  char* Xs = (char*)ldsb + 16384;            // [128 n][128B] swz

  f32x4 acc[2][8];
#pragma unroll
  for (int h = 0; h < 2; ++h)
#pragma unroll
    for (int j = 0; j < 8; ++j) acc[h][j] = (f32x4){0.f, 0.f, 0.f, 0.f};

  const int ro = tid >> 1, haf = tid & 1;
  for (int ks = 0; ks < 4; ++ks) {
    __syncthreads();
    {
      const float* src = W + (size_t)ro * 256 + ks * 64 + haf * 32;
      char* row = Ws + ro * 128;
      const int sw = (ro & 7) << 4;
#pragma unroll
      for (int jj = 0; jj < 4; ++jj) {
        float4 a = ((const float4*)src)[2 * jj];
        float4 c4 = ((const float4*)src)[2 * jj + 1];
        uint4 pk;
        pk.x = pk2(a.x, a.y);  pk.y = pk2(a.z, a.w);
        pk.z = pk2(c4.x, c4.y); pk.w = pk2(c4.z, c4.w);
        *(uint4*)(row + ((haf * 64 + 16 * jj) ^ sw)) = pk;
      }
    }
    {
      const unsigned short* src = xm + ((size_t)(b * 4096) + n0 + ro) * 256 + ks * 64 + haf * 32;
      char* row = Xs + ro * 128;
      const int sw = (ro & 7) << 4;
#pragma unroll
      for (int jj = 0; jj < 4; ++jj)
        *(uint4*)(row + ((haf * 64 + 16 * jj) ^ sw)) = ((const uint4*)src)[jj];
    }
    __syncthreads();
#pragma unroll
    for (int c = 0; c < 2; ++c) {
      bf16x8 af[2], bfr[8];
#pragma unroll
      for (int h = 0; h < 2; ++h) {
        const int r = 32 * w + 16 * h + col;
        af[h] = *(const bf16x8*)(Ws + r * 128 + ((64 * c + 16 * q) ^ ((r & 7) << 4)));
      }
#pragma unroll
      for (int j = 0; j < 8; ++j) {
        const int r = 16 * j + col;
        bfr[j] = *(const bf16x8*)(Xs + r * 128 + ((64 * c + 16 * q) ^ ((r & 7) << 4)));
      }
#pragma unroll
      for (int h = 0; h < 2; ++h)
#pragma unroll
        for (int j = 0; j < 8; ++j)
          acc[h][j] = __builtin_amdgcn_mfma_f32_16x16x32_bf16(af[h], bfr[j], acc[h][j], 0, 0, 0);
    }
  }

  float bs[2][4];
#pragma unroll
  for (int h = 0; h < 2; ++h) {
    const int o0 = 32 * w + 16 * h + 4 * q;
#pragma unroll
    for (int r = 0; r < 4; ++r) bs[h][r] = bias[o0 + r];
  }

  if (ot == 0) {
    char* trb = (char*)ldsb + 32768;         // [128 n][256B] swz, fresh region
#pragma unroll
    for (int h = 0; h < 2; ++h) {
      const int o0 = 32 * w + 16 * h + 4 * q;
#pragma unroll
      for (int j = 0; j < 8; ++j) {
        const int n = 16 * j + col;
        uint2 pkk = make_uint2(pk2(acc[h][j][0] + bs[h][0], acc[h][j][1] + bs[h][1]),
                               pk2(acc[h][j][2] + bs[h][2], acc[h][j][3] + bs[h][3]));
        *(uint2*)(trb + n * 256 + ((2 * o0) ^ ((n & 7) << 4))) = pkk;
      }
    }
    __syncthreads();
    {
      const int n = tid >> 1, h2 = tid & 1;
      unsigned short* dst = (unsigned short*)(ws + F_TH) + ((size_t)(b * 4096) + n0 + n) * 128 + h2 * 64;
      const char* row = trb + n * 256;
      const int sw = (n & 7) << 4;
#pragma unroll
      for (int k = 0; k < 8; ++k)
        ((uint4*)dst)[k] = *(const uint4*)(row + ((128 * h2 + 16 * k) ^ sw));
    }
  } else {
    const int mb = (nt >> 3) * 256 + (nt & 7) * 32;
    unsigned short* phiB = (unsigned short*)(ws + F_PHIB);
#pragma unroll
    for (int h = 0; h < 2; ++h) {
      const int o0 = 32 * w + 16 * h + 4 * q;
#pragma unroll
      for (int jj = 0; jj < 4; ++jj) {
        const int j = (jj >> 1) * 4 + (jj & 1);   // {0,1,4,5}
        f32x4 pm;
#pragma unroll
        for (int r = 0; r < 4; ++r)
          pm[r] = fmaxf(acc[h][j][r], acc[h][j + 2][r]);
#pragma unroll
        for (int r = 0; r < 4; ++r)
          pm[r] = fmaxf(pm[r], __shfl_xor(pm[r], 1));
        if ((col & 1) == 0) {
          const int vp = 8 * (j & 1) + (col >> 1);
          const int m = mb + 16 * (j >> 2) + vp;
          uint2 pkk = make_uint2(pk2(pm[0] + bs[h][0], pm[1] + bs[h][1]),
                                 pk2(pm[2] + bs[h][2], pm[3] + bs[h][3]));
          *(uint2*)(phiB + ((size_t)(b * 1024) + m) * 128 + o0) = pkk;
        }
      }
    }
  }
}

// ---------------------------------------------------------------------------
// g projection from xg (per group, K=256), fused pool -> gB[b][d=2o+gr][m].
// ---------------------------------------------------------------------------
__global__ __launch_bounds__(256)
void k_g_mfma(const float* __restrict__ gw, const float* __restrict__ gb,
              float* __restrict__ ws) {
  const int nt = blockIdx.x, gr = blockIdx.y, b = blockIdx.z;
  const int n0 = nt * 128;
  const int tid = threadIdx.x;
  const int w = tid >> 6, lane = tid & 63, q = lane >> 4, col = lane & 15;
  const unsigned short* xg = (const unsigned short*)(ws + F_XG);

  __shared__ uint4 ldsb[4096];
  char* Ws = (char*)ldsb;
  char* Xs = (char*)ldsb + 16384;

  f32x4 acc[2][8];
#pragma unroll
  for (int h = 0; h < 2; ++h)
#pragma unroll
    for (int j = 0; j < 8; ++j) acc[h][j] = (f32x4){0.f, 0.f, 0.f, 0.f};

  const int ro = tid >> 1, haf = tid & 1;
  for (int ks = 0; ks < 4; ++ks) {
    __syncthreads();
    {
      const float* src = gw + (size_t)ro * 256 + ks * 64 + haf * 32;
      char* row = Ws + ro * 128;
      const int sw = (ro & 7) << 4;
#pragma unroll
      for (int jj = 0; jj < 4; ++jj) {
        float4 a = ((const float4*)src)[2 * jj];
        float4 c4 = ((const float4*)src)[2 * jj + 1];
        uint4 pk;
        pk.x = pk2(a.x, a.y);  pk.y = pk2(a.z, a.w);
        pk.z = pk2(c4.x, c4.y); pk.w = pk2(c4.z, c4.w);
        *(uint4*)(row + ((haf * 64 + 16 * jj) ^ sw)) = pk;
      }
    }
    {
      const unsigned short* src = xg + (((size_t)(b * 2 + gr)) * 4096 + n0 + ro) * 256 + ks * 64 + haf * 32;
      char* row = Xs + ro * 128;
      const int sw = (ro & 7) << 4;
#pragma unroll
      for (int jj = 0; jj < 4; ++jj)
        *(uint4*)(row + ((haf * 64 + 16 * jj) ^ sw)) = ((const uint4*)src)[jj];
    }
    __syncthreads();
#pragma unroll
    for (int c = 0; c < 2; ++c) {
      bf16x8 af[2], bfr[8];
#pragma unroll
      for (int h = 0; h < 2; ++h) {
        const int r = 32 * w + 16 * h + col;
        af[h] = *(const bf16x8*)(Ws + r * 128 + ((64 * c + 16 * q) ^ ((r & 7) << 4)));
      }
#pragma unroll
      for (int j = 0; j < 8; ++j) {
        const int r = 16 * j + col;
        bfr[j] = *(const bf16x8*)(Xs + r * 128 + ((64 * c + 16 * q) ^ ((r & 7) << 4)));
      }
#pragma unroll
      for (int h = 0; h < 2; ++h)
#pragma unroll
        for (int j = 0; j < 8; ++j)
          acc[h][j] = __builtin_amdgcn_mfma_f32_16x16x32_bf16(af[h], bfr[j], acc[h][j], 0, 0, 0);
    }
  }

  const int mb = (nt >> 3) * 256 + (nt & 7) * 32;
  char* pt = (char*)ldsb + 32768;            // [128 o][80B], fresh region
#pragma unroll
  for (int h = 0; h < 2; ++h) {
    const int o0 = 32 * w + 16 * h + 4 * q;
#pragma unroll
    for (int jj = 0; jj < 4; ++jj) {
      const int j = (jj >> 1) * 4 + (jj & 1);
      f32x4 pm;
#pragma unroll
      for (int r = 0; r < 4; ++r)
        pm[r] = fmaxf(acc[h][j][r], acc[h][j + 2][r]);
#pragma unroll
      for (int r = 0; r < 4; ++r)
        pm[r] = fmaxf(pm[r], __shfl_xor(pm[r], 1));
      if ((col & 1) == 0) {
        const int ml = 16 * (j >> 2) + 8 * (j & 1) + (col >> 1);
#pragma unroll
        for (int r = 0; r < 4; ++r)
          *(unsigned short*)(pt + (o0 + r) * 80 + ml * 2) = f2bf(pm[r] + gb[o0 + r]);
      }
    }
  }
  __syncthreads();
  if (tid < 128) {
    const int o = tid;
    const char* row = pt + o * 80;
    unsigned short* dst = (unsigned short*)(ws + F_GB) + ((size_t)(b * 256) + 2 * o + gr) * 1024 + mb;
#pragma unroll
    for (int k = 0; k < 4; ++k)
      ((uint4*)dst)[k] = *(const uint4*)(row + 16 * k);
  }
}

// ---------------------------------------------------------------------------
// MFMA flash attention v9: R10 loop + d-split waves. 8 waves = 4 row-groups
// x 2 d-halves; each wave 32 rows (2 col-groups) x 128 d. V-fragment reads
// halve vs R10 (vf shared across cg, d-half per wave). No m-split, single y.
// K dbuf 2x8KB, V pair-dbuf 2x32KB, P [4 rg][2 cg][16 col][128B] (R10 layout).
// LDS 96KB. One barrier/iter. __launch_bounds__(512,2) to avoid spills.
// ---------------------------------------------------------------------------
#define KVB 32
#define NIT 32
__global__ __launch_bounds__(512, 2)
void k_attn_mfma(float* __restrict__ ws) {
  const int b = blockIdx.x;          // 8 batches -> 8 XCDs (round-robin)
  const int n0 = blockIdx.y * 128;
  const int tid = threadIdx.x;
  const int w = tid >> 6;
  const int lane = tid & 63;
  const int q = lane >> 4;
  const int col = lane & 15;
  const int g = w & 3;               // row-group (rows 32g..32g+31)
  const int dh = w >> 2;             // d-half (d 128*dh..+127)
  const int ksw = (col & 7) << 4;

  __shared__ char lds[98304];
  // kbuf[2]: 2x8KB @0        (K tile [32 m][256B], row-swz ((m&7)<<4))
  // vbuf[2]: 2x32KB @16384   (V^T pair-tile [256 d][128B], row-swz ((d&7)<<4))
  // P: 16KB @81920           [4 rg][2 cg][16 col][128B], ksw swizzle
  char* pbase = lds + 81920 + g * 4096;

  const unsigned short* thetaB = (const unsigned short*)(ws + F_TH);
  const char* phiBb = (const char*)((const unsigned short*)(ws + F_PHIB) + (size_t)b * 1024 * 128);
  const char* gBb   = (const char*)((const unsigned short*)(ws + F_GB) + (size_t)b * 256 * 1024);
  unsigned short* yB = (unsigned short*)(ws + F_Y);

  // staging lane geometry (pre-swizzled global source, linear LDS dest)
  const int kr0 = lane >> 4;               // K: row within 4-row chunk
  const int kso = (lane & 15) * 16;
  const int vr0 = lane >> 3;               // V: row within 8-row chunk
  const int vso = (lane & 7) * 16;

  // Q fragments: 2 col-groups of 16 rows each
  bf16x8 qf[2][4];
#pragma unroll
  for (int cg = 0; cg < 2; ++cg) {
    const unsigned short* qp = thetaB +
        ((size_t)(b * 4096 + n0 + 32 * g + 16 * cg + col)) * 128 + 8 * q;
#pragma unroll
    for (int c = 0; c < 4; ++c) qf[cg][c] = *(const bf16x8*)(qp + 32 * c);
  }

  f32x4 ot[2][8];
#pragma unroll
  for (int cg = 0; cg < 2; ++cg)
#pragma unroll
    for (int t = 0; t < 8; ++t) ot[cg][t] = (f32x4){0.f, 0.f, 0.f, 0.f};
  float mrun[2] = {-1e30f, -1e30f}, lsum[2] = {0.f, 0.f};

  // prologue: K tile0 (wave w -> chunk w) + V pair0 (wave w -> chunks 4w..4w+3)
  {
    const int r = 4 * w + kr0;
    gload_lds16(phiBb + (size_t)r * 256 + (kso ^ ((r & 7) << 4)), lds + w * 1024);
#pragma unroll
    for (int j = 0; j < 4; ++j) {
      const int c = 4 * w + j;
      const int d = 8 * c + vr0;
      gload_lds16(gBb + (size_t)d * 2048 + (vso ^ ((d & 7) << 4)),
                  lds + 16384 + c * 1024);
    }
  }
  __syncthreads();

  for (int it = 0; it < NIT; ++it) {
    char* ktc = lds + (it & 1) * 8192;
    char* vtc = lds + 16384 + ((it >> 1) & 1) * 32768;
    const int par = it & 1;

    // stage next K tile into the other K buffer
    if (it + 1 < NIT) {
      const int r = 4 * w + kr0;
      gload_lds16(phiBb + (size_t)((it + 1) * KVB + r) * 256 + (kso ^ ((r & 7) << 4)),
                  lds + ((it & 1) ^ 1) * 8192 + w * 1024);
    }
    // stage next V pair into the other V buffer (pair boundary)
    if (par == 0 && (it >> 1) + 1 < 16) {
      const size_t vm = (size_t)(((it >> 1) + 1) * 64) * 2;
#pragma unroll
      for (int j = 0; j < 4; ++j) {
        const int c = 4 * w + j;
        const int d = 8 * c + vr0;
        gload_lds16(gBb + (size_t)d * 2048 + vm + (vso ^ ((d & 7) << 4)),
                    lds + 16384 + (((it >> 1) & 1) ^ 1) * 32768 + c * 1024);
      }
    }

    // S^T = K . Q^T : kf shared by both col-groups
    f32x4 st[2][2];
#pragma unroll
    for (int cg = 0; cg < 2; ++cg)
#pragma unroll
      for (int s = 0; s < 2; ++s) st[cg][s] = (f32x4){0.f, 0.f, 0.f, 0.f};
    __builtin_amdgcn_s_setprio(1);
#pragma unroll
    for (int c = 0; c < 4; ++c)
#pragma unroll
      for (int s = 0; s < 2; ++s) {
        const bf16x8 kf = *(const bf16x8*)(ktc + (16 * s + col) * 256 +
                                           ((64 * c + 16 * q) ^ ksw));
        st[0][s] = __builtin_amdgcn_mfma_f32_16x16x32_bf16(kf, qf[0][c], st[0][s], 0, 0, 0);
        st[1][s] = __builtin_amdgcn_mfma_f32_16x16x32_bf16(kf, qf[1][c], st[1][s], 0, 0, 0);
      }
    __builtin_amdgcn_s_setprio(0);

    // online softmax (defer-max, threshold 8) + P write, per col-group.
    // d-half twins compute identical values; P region shared per (rg,cg) —
    // twins write byte-identical data (benign duplicate, R11-verified).
    bf16x8 pf[2];
#pragma unroll
    for (int cg = 0; cg < 2; ++cg) {
      float pmax = -1e30f;
#pragma unroll
      for (int s = 0; s < 2; ++s)
#pragma unroll
        for (int r = 0; r < 4; ++r) pmax = fmaxf(pmax, st[cg][s][r]);
      pmax = fmaxf(pmax, __shfl_xor(pmax, 16));
      pmax = fmaxf(pmax, __shfl_xor(pmax, 32));
      if (!__all(pmax - mrun[cg] <= 8.f)) {
        const float mnew = fmaxf(mrun[cg], pmax);
        const float scl = __expf(mrun[cg] - mnew);
        mrun[cg] = mnew;
        lsum[cg] *= scl;
#pragma unroll
        for (int t = 0; t < 8; ++t) {
          ot[cg][t][0] *= scl; ot[cg][t][1] *= scl;
          ot[cg][t][2] *= scl; ot[cg][t][3] *= scl;
        }
      }
      float rsum = 0.f;
#pragma unroll
      for (int s = 0; s < 2; ++s)
#pragma unroll
        for (int r = 0; r < 4; ++r) {
          st[cg][s][r] = __expf(st[cg][s][r] - mrun[cg]);
          rsum += st[cg][s][r];
        }
      rsum += __shfl_xor(rsum, 16);
      rsum += __shfl_xor(rsum, 32);
      lsum[cg] += rsum;

      char* prow = pbase + cg * 2048 + col * 128;
#pragma unroll
      for (int s = 0; s < 2; ++s)
#pragma unroll
        for (int hp = 0; hp < 2; ++hp)
          *(unsigned int*)(prow + ((32 * s + 8 * q + 4 * hp) ^ ksw)) =
              pk2(st[cg][s][2 * hp], st[cg][s][2 * hp + 1]);
      pf[cg] = *(const bf16x8*)(prow + ((16 * q) ^ ksw));
    }

    // O^T += V^T . P^T  (this wave's d-half only; vf shared across cg)
    __builtin_amdgcn_s_setprio(1);
#pragma unroll
    for (int t = 0; t < 8; ++t) {
      const int d = 128 * dh + 16 * t + col;
      const bf16x8 vf = *(const bf16x8*)(vtc + d * 128 +
                                         ((64 * par + 16 * q) ^ ((d & 7) << 4)));
      ot[0][t] = __builtin_amdgcn_mfma_f32_16x16x32_bf16(vf, pf[0], ot[0][t], 0, 0, 0);
      ot[1][t] = __builtin_amdgcn_mfma_f32_16x16x32_bf16(vf, pf[1], ot[1][t], 0, 0, 0);
    }
    __builtin_amdgcn_s_setprio(0);

    __syncthreads();   // staged tiles complete + all waves done with cur bufs
  }

  // epilogue: y[b][gr][n][i] bf16 via LDS transpose.
  // d = 128*dh + 16t + 4q + r -> gr = r&1, i = 64*dh + 8t + 2q + (r>>1)
  char* yt = lds;                    // [256 rows (gr*128+nl)][256B] swz (64KB)
#pragma unroll
  for (int cg = 0; cg < 2; ++cg) {
    const float i0 = 1.f / lsum[cg];
    const int nl = 32 * g + 16 * cg + col;
    const int swn = (nl & 7) << 4;
#pragma unroll
    for (int t = 0; t < 8; ++t) {
      const unsigned int w0 = pk2(ot[cg][t][0] * i0, ot[cg][t][2] * i0);
      const unsigned int w1 = pk2(ot[cg][t][1] * i0, ot[cg][t][3] * i0);
      const int bo = 128 * dh + 16 * t + 4 * q;
      *(unsigned int*)(yt + nl * 256 + (bo ^ swn)) = w0;
      *(unsigned int*)(yt + (128 + nl) * 256 + (bo ^ swn)) = w1;
    }
  }
  __syncthreads();
  {
    const int row = tid >> 1, h2 = tid & 1;
    const int gr = row >> 7, n = row & 127;
    unsigned short* dst = yB + (((size_t)(b * 2 + gr)) * 4096 + n0 + n) * 128 + h2 * 64;
    const char* srow = yt + row * 256;
    const int sw = (n & 7) << 4;
#pragma unroll
    for (int k = 0; k < 8; ++k)
      ((uint4*)dst)[k] = *(const uint4*)(srow + ((128 * h2 + 16 * k) ^ sw));
  }
}

// ---------------------------------------------------------------------------
// Final W conv (MFMA, K=128 per group) + bias + residual.
// ---------------------------------------------------------------------------
__global__ __launch_bounds__(256)
void k_final_mfma(const float* __restrict__ x,
                  const float* __restrict__ Ww, const float* __restrict__ Wb,
                  const float* __restrict__ ws, float* __restrict__ out) {
  const int nt = blockIdx.x, gq = blockIdx.y, b = blockIdx.z;
  const int gr = gq & 1, ob = (gq >> 1) * 128;
  const int n0 = nt * 128;
  const int tid = threadIdx.x;
  const int w = tid >> 6, lane = tid & 63, q = lane >> 4, col = lane & 15;
  const unsigned short* yb = (const unsigned short*)(ws + F_Y);

  __shared__ uint4 ldsb[4096];
  char* As = (char*)ldsb;
  char* Bs = (char*)ldsb + 16384;

  f32x4 acc[2][8];
#pragma unroll
  for (int h = 0; h < 2; ++h)
#pragma unroll
    for (int j = 0; j < 8; ++j) acc[h][j] = (f32x4){0.f, 0.f, 0.f, 0.f};

  const int ro = tid >> 1, haf = tid & 1;
  for (int ks = 0; ks < 2; ++ks) {
    __syncthreads();
    {
      const float* src = Ww + (size_t)(ob + ro) * 128 + ks * 64 + haf * 32;
      char* row = As + ro * 128;
      const int sw = (ro & 7) << 4;
#pragma unroll
      for (int jj = 0; jj < 4; ++jj) {
        float4 a = ((const float4*)src)[2 * jj];
        float4 c4 = ((const float4*)src)[2 * jj + 1];
        uint4 pk;
        pk.x = pk2(a.x, a.y);  pk.y = pk2(a.z, a.w);
        pk.z = pk2(c4.x, c4.y); pk.w = pk2(c4.z, c4.w);
        *(uint4*)(row + ((haf * 64 + 16 * jj) ^ sw)) = pk;
      }
    }
    {
      const unsigned short* src = yb + (((size_t)(b * 2 + gr)) * 4096 + n0 + ro) * 128 + ks * 64 + haf * 32;
      char* row = Bs + ro * 128;
      const int sw = (ro & 7) << 4;
#pragma unroll
      for (int jj = 0; jj < 4; ++jj)
        *(uint4*)(row + ((haf * 64 + 16 * jj) ^ sw)) = ((const uint4*)src)[jj];
    }
    __syncthreads();
#pragma unroll
    for (int c = 0; c < 2; ++c) {
      bf16x8 af[2], bfr[8];
#pragma unroll
      for (int h = 0; h < 2; ++h) {
        const int r = 32 * w + 16 * h + col;
        af[h] = *(const bf16x8*)(As + r * 128 + ((64 * c + 16 * q) ^ ((r & 7) << 4)));
      }
#pragma unroll
      for (int j = 0; j < 8; ++j) {
        const int r = 16 * j + col;
        bfr[j] = *(const bf16x8*)(Bs + r * 128 + ((64 * c + 16 * q) ^ ((r & 7) << 4)));
      }
#pragma unroll
      for (int h = 0; h < 2; ++h)
#pragma unroll
        for (int j = 0; j < 8; ++j)
          acc[h][j] = __builtin_amdgcn_mfma_f32_16x16x32_bf16(af[h], bfr[j], acc[h][j], 0, 0, 0);
    }
  }

  __syncthreads();                           // reuse whole LDS: f32 [128 o][512B]
  char* ft = (char*)ldsb;
#pragma unroll
  for (int h = 0; h < 2; ++h) {
    const int o0 = 32 * w + 16 * h + 4 * q;
#pragma unroll
    for (int j = 0; j < 8; ++j) {
      const int n = 16 * j + col;
#pragma unroll
      for (int r = 0; r < 4; ++r)
        *(float*)(ft + (o0 + r) * 512 + ((n * 4) ^ (((o0 + r) & 7) << 4))) = acc[h][j][r];
    }
  }
  __syncthreads();
  {
    const int o = tid >> 1, h2 = tid & 1;
    const float bsv = Wb[ob + o];
    const int ch = 2 * (ob + o) + gr;
    const size_t base = ((size_t)(b * 512 + ch)) * 4096 + n0 + h2 * 64;
    const char* row = ft + o * 512;
    const int sw = (o & 7) << 4;
#pragma unroll
    for (int k = 0; k < 16; ++k) {
      f32x4 v = *(const f32x4*)(row + ((256 * h2 + 16 * k) ^ sw));
      float4 xv = ((const float4*)(x + base))[k];
      ((float4*)(out + base))[k] = make_float4(v[0] + bsv + xv.x, v[1] + bsv + xv.y,
                                               v[2] + bsv + xv.z, v[3] + bsv + xv.w);
    }
  }
}

extern "C" void kernel_launch(void* const* d_in, const int* in_sizes, int n_in,
                              void* d_out, int out_size, void* d_ws, size_t ws_size,
                              hipStream_t stream) {
  const float* x  = (const float*)d_in[0];
  const float* gw = (const float*)d_in[1];
  const float* gb = (const float*)d_in[2];
  const float* tw = (const float*)d_in[3];
  const float* tb = (const float*)d_in[4];
  const float* pw = (const float*)d_in[5];
  const float* pb = (const float*)d_in[6];
  const float* Ww = (const float*)d_in[7];
  const float* Wb = (const float*)d_in[8];
  float* out = (float*)d_out;
  float* ws  = (float*)d_ws;

  k_prep<<<dim3(16, 8, 8), 256, 0, stream>>>(x, ws);
  k_proj_mfma<<<dim3(32, 2, 8), 256, 0, stream>>>(tw, tb, pw, pb, ws);
  k_g_mfma<<<dim3(32, 2, 8), 256, 0, stream>>>(gw, gb, ws);
  k_attn_mfma<<<dim3(8, 32), 512, 0, stream>>>(ws);
  k_final_mfma<<<dim3(32, 4, 8), 256, 0, stream>>>(x, Ww, Wb, ws, out);
}

// Round 13
// 156.625 us; speedup vs baseline: 1.3344x; 1.1003x over previous
//
#include <hip/hip_runtime.h>

// Workspace float offsets
#define F_XM    0u          // bf16 xm[8][4096][256]      -> 4,194,304 f
#define F_XG    4194304u    // bf16 xg[8][2][4096][256]   -> 8,388,608 f
#define F_Y     4194304u    // bf16 y[8][2][4096][128] aliases xg (dead after k_g)
#define F_TH    12582912u   // bf16 theta[8][4096][128]   -> 2,097,152 f
#define F_PHIB  14680064u   // bf16 phi[8][1024][128]     ->   524,288 f
#define F_GB    15204352u   // bf16 g[8][256][1024]       -> 1,048,576 f
// total 16,252,928 floats = 65.0 MB

typedef __attribute__((ext_vector_type(4))) float f32x4;
typedef __attribute__((ext_vector_type(8))) short bf16x8;

__device__ __forceinline__ unsigned short f2bf(float f) {
  union { unsigned int i; float f; } x; x.f = f;
  unsigned int r = x.i + 0x7fffu + ((x.i >> 16) & 1u);
  return (unsigned short)(r >> 16);
}
__device__ __forceinline__ unsigned int pk2(float a, float b) {
  return (unsigned int)f2bf(a) | ((unsigned int)f2bf(b) << 16);
}
__device__ __forceinline__ void gload_lds16(const void* g, void* l) {
  __builtin_amdgcn_global_load_lds(
      (const __attribute__((address_space(1))) unsigned int*)g,
      (__attribute__((address_space(3))) unsigned int*)l, 16, 0, 0);
}

// ---------------------------------------------------------------------------
// Prep: x f32 [b][512][4096] -> bf16 xm[b][n][256] (mean over group pair) and
// xg[b][gr][n][256] (K-contiguous layouts for the MFMA GEMMs).
// ---------------------------------------------------------------------------
__global__ __launch_bounds__(256)
void k_prep(const float* __restrict__ x, float* __restrict__ ws) {
  const int nt = blockIdx.x, ct = blockIdx.y, b = blockIdx.z;
  const int n0 = nt * 256, c0 = ct * 64;
  const int tid = threadIdx.x;
  __shared__ uint4 ldsb[4096];               // 64 KB: f32 [64 c][1024B] swz
  char* lds = (char*)ldsb;
  {
    const int c = tid >> 2;
    const int nch = (tid & 3) * 64;
    const float* src = x + ((size_t)(b * 512 + c0 + c)) * 4096 + n0 + nch;
    char* row = lds + c * 1024;
    const int sw = (c & 7) << 4;
    const int bb = nch * 4;
#pragma unroll
    for (int k = 0; k < 16; ++k)
      *(uint4*)(row + ((bb + 16 * k) ^ sw)) = ((const uint4*)src)[k];
  }
  __syncthreads();
  {
    const int n = tid;
    unsigned int u0[16], u1[16], um[16];
#pragma unroll
    for (int jc = 0; jc < 4; ++jc) {
      float v[16];
#pragma unroll
      for (int cc = 0; cc < 16; ++cc) {
        const int c = 16 * jc + cc;
        v[cc] = *(const float*)(lds + c * 1024 + ((n * 4) ^ ((c & 7) << 4)));
      }
#pragma unroll
      for (int s = 0; s < 4; ++s) {
        u0[4 * jc + s] = pk2(v[4 * s], v[4 * s + 2]);
        u1[4 * jc + s] = pk2(v[4 * s + 1], v[4 * s + 3]);
        um[4 * jc + s] = pk2(0.5f * (v[4 * s] + v[4 * s + 1]),
                             0.5f * (v[4 * s + 2] + v[4 * s + 3]));
      }
    }
    unsigned short* xm = (unsigned short*)(ws + F_XM);
    unsigned short* xg = (unsigned short*)(ws + F_XG);
    uint4* d0 = (uint4*)(xg + (((size_t)(b * 2 + 0) * 4096) + n0 + n) * 256 + (c0 >> 1));
    uint4* d1 = (uint4*)(xg + (((size_t)(b * 2 + 1) * 4096) + n0 + n) * 256 + (c0 >> 1));
    uint4* dm = (uint4*)(xm + ((size_t)(b * 4096) + n0 + n) * 256 + (c0 >> 1));
#pragma unroll
    for (int s = 0; s < 4; ++s) {
      d0[s] = make_uint4(u0[4 * s], u0[4 * s + 1], u0[4 * s + 2], u0[4 * s + 3]);
      d1[s] = make_uint4(u1[4 * s], u1[4 * s + 1], u1[4 * s + 2], u1[4 * s + 3]);
      dm[s] = make_uint4(um[4 * s], um[4 * s + 1], um[4 * s + 2], um[4 * s + 3]);
    }
  }
}

// ---------------------------------------------------------------------------
// theta & phi projections from xm (K=256). Out tile 128 o x 128 n, 4 waves.
// ot=0: theta[b][n][o] bf16 (LDS transpose). ot=1: pooled phiB[b][m][o] bf16.
// ---------------------------------------------------------------------------
__global__ __launch_bounds__(256)
void k_proj_mfma(const float* __restrict__ tw, const float* __restrict__ tb,
                 const float* __restrict__ pw, const float* __restrict__ pb,
                 float* __restrict__ ws) {
  const int nt = blockIdx.x, ot = blockIdx.y, b = blockIdx.z;
  const int n0 = nt * 128;
  const int tid = threadIdx.x;
  const int w = tid >> 6, lane = tid & 63, q = lane >> 4, col = lane & 15;
  const float* W = ot ? pw : tw;
  const float* bias = ot ? pb : tb;
  const unsigned short* xm = (const unsigned short*)(ws + F_XM);

  __shared__ uint4 ldsb[4096];               // 64 KB
  char* Ws = (char*)ldsb;                    // [128 o][128B] swz
  char* Xs = (char*)ldsb + 16384;            // [128 n][128B] swz

  f32x4 acc[2][8];
#pragma unroll
  for (int h = 0; h < 2; ++h)
#pragma unroll
    for (int j = 0; j < 8; ++j) acc[h][j] = (f32x4){0.f, 0.f, 0.f, 0.f};

  const int ro = tid >> 1, haf = tid & 1;
  for (int ks = 0; ks < 4; ++ks) {
    __syncthreads();
    {
      const float* src = W + (size_t)ro * 256 + ks * 64 + haf * 32;
      char* row = Ws + ro * 128;
      const int sw = (ro & 7) << 4;
#pragma unroll
      for (int jj = 0; jj < 4; ++jj) {
        float4 a = ((const float4*)src)[2 * jj];
        float4 c4 = ((const float4*)src)[2 * jj + 1];
        uint4 pk;
        pk.x = pk2(a.x, a.y);  pk.y = pk2(a.z, a.w);
        pk.z = pk2(c4.x, c4.y); pk.w = pk2(c4.z, c4.w);
        *(uint4*)(row + ((haf * 64 + 16 * jj) ^ sw)) = pk;
      }
    }
    {
      const unsigned short* src = xm + ((size_t)(b * 4096) + n0 + ro) * 256 + ks * 64 + haf * 32;
      char* row = Xs + ro * 128;
      const int sw = (ro & 7) << 4;
#pragma unroll
      for (int jj = 0; jj < 4; ++jj)
        *(uint4*)(row + ((haf * 64 + 16 * jj) ^ sw)) = ((const uint4*)src)[jj];
    }
    __syncthreads();
#pragma unroll
    for (int c = 0; c < 2; ++c) {
      bf16x8 af[2], bfr[8];
#pragma unroll
      for (int h = 0; h < 2; ++h) {
        const int r = 32 * w + 16 * h + col;
        af[h] = *(const bf16x8*)(Ws + r * 128 + ((64 * c + 16 * q) ^ ((r & 7) << 4)));
      }
#pragma unroll
      for (int j = 0; j < 8; ++j) {
        const int r = 16 * j + col;
        bfr[j] = *(const bf16x8*)(Xs + r * 128 + ((64 * c + 16 * q) ^ ((r & 7) << 4)));
      }
#pragma unroll
      for (int h = 0; h < 2; ++h)
#pragma unroll
        for (int j = 0; j < 8; ++j)
          acc[h][j] = __builtin_amdgcn_mfma_f32_16x16x32_bf16(af[h], bfr[j], acc[h][j], 0, 0, 0);
    }
  }

  float bs[2][4];
#pragma unroll
  for (int h = 0; h < 2; ++h) {
    const int o0 = 32 * w + 16 * h + 4 * q;
#pragma unroll
    for (int r = 0; r < 4; ++r) bs[h][r] = bias[o0 + r];
  }

  if (ot == 0) {
    char* trb = (char*)ldsb + 32768;         // [128 n][256B] swz, fresh region
#pragma unroll
    for (int h = 0; h < 2; ++h) {
      const int o0 = 32 * w + 16 * h + 4 * q;
#pragma unroll
      for (int j = 0; j < 8; ++j) {
        const int n = 16 * j + col;
        uint2 pkk = make_uint2(pk2(acc[h][j][0] + bs[h][0], acc[h][j][1] + bs[h][1]),
                               pk2(acc[h][j][2] + bs[h][2], acc[h][j][3] + bs[h][3]));
        *(uint2*)(trb + n * 256 + ((2 * o0) ^ ((n & 7) << 4))) = pkk;
      }
    }
    __syncthreads();
    {
      const int n = tid >> 1, h2 = tid & 1;
      unsigned short* dst = (unsigned short*)(ws + F_TH) + ((size_t)(b * 4096) + n0 + n) * 128 + h2 * 64;
      const char* row = trb + n * 256;
      const int sw = (n & 7) << 4;
#pragma unroll
      for (int k = 0; k < 8; ++k)
        ((uint4*)dst)[k] = *(const uint4*)(row + ((128 * h2 + 16 * k) ^ sw));
    }
  } else {
    const int mb = (nt >> 3) * 256 + (nt & 7) * 32;
    unsigned short* phiB = (unsigned short*)(ws + F_PHIB);
#pragma unroll
    for (int h = 0; h < 2; ++h) {
      const int o0 = 32 * w + 16 * h + 4 * q;
#pragma unroll
      for (int jj = 0; jj < 4; ++jj) {
        const int j = (jj >> 1) * 4 + (jj & 1);   // {0,1,4,5}
        f32x4 pm;
#pragma unroll
        for (int r = 0; r < 4; ++r)
          pm[r] = fmaxf(acc[h][j][r], acc[h][j + 2][r]);
#pragma unroll
        for (int r = 0; r < 4; ++r)
          pm[r] = fmaxf(pm[r], __shfl_xor(pm[r], 1));
        if ((col & 1) == 0) {
          const int vp = 8 * (j & 1) + (col >> 1);
          const int m = mb + 16 * (j >> 2) + vp;
          uint2 pkk = make_uint2(pk2(pm[0] + bs[h][0], pm[1] + bs[h][1]),
                                 pk2(pm[2] + bs[h][2], pm[3] + bs[h][3]));
          *(uint2*)(phiB + ((size_t)(b * 1024) + m) * 128 + o0) = pkk;
        }
      }
    }
  }
}

// ---------------------------------------------------------------------------
// g projection from xg (per group, K=256), fused pool -> gB[b][d=2o+gr][m].
// ---------------------------------------------------------------------------
__global__ __launch_bounds__(256)
void k_g_mfma(const float* __restrict__ gw, const float* __restrict__ gb,
              float* __restrict__ ws) {
  const int nt = blockIdx.x, gr = blockIdx.y, b = blockIdx.z;
  const int n0 = nt * 128;
  const int tid = threadIdx.x;
  const int w = tid >> 6, lane = tid & 63, q = lane >> 4, col = lane & 15;
  const unsigned short* xg = (const unsigned short*)(ws + F_XG);

  __shared__ uint4 ldsb[4096];
  char* Ws = (char*)ldsb;
  char* Xs = (char*)ldsb + 16384;

  f32x4 acc[2][8];
#pragma unroll
  for (int h = 0; h < 2; ++h)
#pragma unroll
    for (int j = 0; j < 8; ++j) acc[h][j] = (f32x4){0.f, 0.f, 0.f, 0.f};

  const int ro = tid >> 1, haf = tid & 1;
  for (int ks = 0; ks < 4; ++ks) {
    __syncthreads();
    {
      const float* src = gw + (size_t)ro * 256 + ks * 64 + haf * 32;
      char* row = Ws + ro * 128;
      const int sw = (ro & 7) << 4;
#pragma unroll
      for (int jj = 0; jj < 4; ++jj) {
        float4 a = ((const float4*)src)[2 * jj];
        float4 c4 = ((const float4*)src)[2 * jj + 1];
        uint4 pk;
        pk.x = pk2(a.x, a.y);  pk.y = pk2(a.z, a.w);
        pk.z = pk2(c4.x, c4.y); pk.w = pk2(c4.z, c4.w);
        *(uint4*)(row + ((haf * 64 + 16 * jj) ^ sw)) = pk;
      }
    }
    {
      const unsigned short* src = xg + (((size_t)(b * 2 + gr)) * 4096 + n0 + ro) * 256 + ks * 64 + haf * 32;
      char* row = Xs + ro * 128;
      const int sw = (ro & 7) << 4;
#pragma unroll
      for (int jj = 0; jj < 4; ++jj)
        *(uint4*)(row + ((haf * 64 + 16 * jj) ^ sw)) = ((const uint4*)src)[jj];
    }
    __syncthreads();
#pragma unroll
    for (int c = 0; c < 2; ++c) {
      bf16x8 af[2], bfr[8];
#pragma unroll
      for (int h = 0; h < 2; ++h) {
        const int r = 32 * w + 16 * h + col;
        af[h] = *(const bf16x8*)(Ws + r * 128 + ((64 * c + 16 * q) ^ ((r & 7) << 4)));
      }
#pragma unroll
      for (int j = 0; j < 8; ++j) {
        const int r = 16 * j + col;
        bfr[j] = *(const bf16x8*)(Xs + r * 128 + ((64 * c + 16 * q) ^ ((r & 7) << 4)));
      }
#pragma unroll
      for (int h = 0; h < 2; ++h)
#pragma unroll
        for (int j = 0; j < 8; ++j)
          acc[h][j] = __builtin_amdgcn_mfma_f32_16x16x32_bf16(af[h], bfr[j], acc[h][j], 0, 0, 0);
    }
  }

  const int mb = (nt >> 3) * 256 + (nt & 7) * 32;
  char* pt = (char*)ldsb + 32768;            // [128 o][80B], fresh region
#pragma unroll
  for (int h = 0; h < 2; ++h) {
    const int o0 = 32 * w + 16 * h + 4 * q;
#pragma unroll
    for (int jj = 0; jj < 4; ++jj) {
      const int j = (jj >> 1) * 4 + (jj & 1);
      f32x4 pm;
#pragma unroll
      for (int r = 0; r < 4; ++r)
        pm[r] = fmaxf(acc[h][j][r], acc[h][j + 2][r]);
#pragma unroll
      for (int r = 0; r < 4; ++r)
        pm[r] = fmaxf(pm[r], __shfl_xor(pm[r], 1));
      if ((col & 1) == 0) {
        const int ml = 16 * (j >> 2) + 8 * (j & 1) + (col >> 1);
#pragma unroll
        for (int r = 0; r < 4; ++r)
          *(unsigned short*)(pt + (o0 + r) * 80 + ml * 2) = f2bf(pm[r] + gb[o0 + r]);
      }
    }
  }
  __syncthreads();
  if (tid < 128) {
    const int o = tid;
    const char* row = pt + o * 80;
    unsigned short* dst = (unsigned short*)(ws + F_GB) + ((size_t)(b * 256) + 2 * o + gr) * 1024 + mb;
#pragma unroll
    for (int k = 0; k < 4; ++k)
      ((uint4*)dst)[k] = *(const uint4*)(row + 16 * k);
  }
}

// ---------------------------------------------------------------------------
// MFMA flash attention v10: R10 structure with 2 iterations per barrier.
// K 4-buffered (2 tiles staged per super-iter), V pair-dbuf (both halves of a
// super-iter in one buffer), merged softmax over 16 scores (one rescale-check,
// 16 independent exps), dual wave-private P regions. 16 barriers total.
// LDS 128KB. 8 waves x 16 rows, grid (8 b, 32 nt).
// ---------------------------------------------------------------------------
#define NSIT 16
__global__ __launch_bounds__(512)
void k_attn_mfma(float* __restrict__ ws) {
  const int b = blockIdx.x;          // 8 batches -> 8 XCDs (round-robin)
  const int n0 = blockIdx.y * 128;
  const int tid = threadIdx.x;
  const int w = tid >> 6;            // 0..7
  const int lane = tid & 63;
  const int q = lane >> 4;
  const int col = lane & 15;
  const int ksw = (col & 7) << 4;

  __shared__ char lds[131072];
  // kbuf[4]: 4x8KB @0        (K tile [32 m][256B], row-swz ((m&7)<<4))
  // vbuf[2]: 2x32KB @32768   (V^T pair-tile [256 d][128B], row-swz ((d&7)<<4))
  // P: 2x2KB per wave @98304 ([16 col][128B], ksw swizzle)
  char* plw0 = lds + 98304 + w * 4096;
  char* plw1 = plw0 + 2048;

  const unsigned short* thetaB = (const unsigned short*)(ws + F_TH);
  const char* phiBb = (const char*)((const unsigned short*)(ws + F_PHIB) + (size_t)b * 1024 * 128);
  const char* gBb   = (const char*)((const unsigned short*)(ws + F_GB) + (size_t)b * 256 * 1024);
  unsigned short* yB = (unsigned short*)(ws + F_Y);

  // staging lane geometry (pre-swizzled global source, linear LDS dest)
  const int kr0 = lane >> 4;               // K: row within 4-row chunk
  const int kso = (lane & 15) * 16;
  const int vr0 = lane >> 3;               // V: row within 8-row chunk
  const int vso = (lane & 7) * 16;

  bf16x8 qf[4];
  {
    const unsigned short* qp = thetaB + ((size_t)(b * 4096 + n0 + 16 * w + col)) * 128 + 8 * q;
#pragma unroll
    for (int c = 0; c < 4; ++c) qf[c] = *(const bf16x8*)(qp + 32 * c);
  }

  f32x4 ot[16];
#pragma unroll
  for (int t = 0; t < 16; ++t) ot[t] = (f32x4){0.f, 0.f, 0.f, 0.f};
  float mrun = -1e30f, lsum = 0.f;

  // prologue: K0 -> kbuf0, K1 -> kbuf1, V pair0 -> vbuf0
  {
    const int r = 4 * w + kr0;
    gload_lds16(phiBb + (size_t)r * 256 + (kso ^ ((r & 7) << 4)), lds + w * 1024);
    gload_lds16(phiBb + (size_t)(32 + r) * 256 + (kso ^ ((r & 7) << 4)),
                lds + 8192 + w * 1024);
#pragma unroll
    for (int j = 0; j < 4; ++j) {
      const int c = 4 * w + j;
      const int d = 8 * c + vr0;
      gload_lds16(gBb + (size_t)d * 2048 + (vso ^ ((d & 7) << 4)),
                  lds + 32768 + c * 1024);
    }
  }
  __syncthreads();

  for (int sit = 0; sit < NSIT; ++sit) {
    char* kt0 = lds + ((2 * sit) & 3) * 8192;
    char* kt1 = lds + ((2 * sit + 1) & 3) * 8192;
    char* vtc = lds + 32768 + (sit & 1) * 32768;

    // stage next super-iter's tiles (async; complete by end-of-sit barrier)
    if (sit + 1 < NSIT) {
      const int r = 4 * w + kr0;
      const int swk = (kso ^ ((r & 7) << 4));
      gload_lds16(phiBb + (size_t)((2 * sit + 2) * 32 + r) * 256 + swk,
                  lds + ((2 * sit + 2) & 3) * 8192 + w * 1024);
      gload_lds16(phiBb + (size_t)((2 * sit + 3) * 32 + r) * 256 + swk,
                  lds + ((2 * sit + 3) & 3) * 8192 + w * 1024);
      const size_t vm = (size_t)((sit + 1) * 64) * 2;
#pragma unroll
      for (int j = 0; j < 4; ++j) {
        const int c = 4 * w + j;
        const int d = 8 * c + vr0;
        gload_lds16(gBb + (size_t)d * 2048 + vm + (vso ^ ((d & 7) << 4)),
                    lds + 32768 + ((sit & 1) ^ 1) * 32768 + c * 1024);
      }
    }

    // QK^T for both iterations (independent MFMA chains)
    f32x4 st0[2], st1[2];
#pragma unroll
    for (int s = 0; s < 2; ++s) {
      st0[s] = (f32x4){0.f, 0.f, 0.f, 0.f};
      st1[s] = (f32x4){0.f, 0.f, 0.f, 0.f};
    }
    __builtin_amdgcn_s_setprio(1);
#pragma unroll
    for (int c = 0; c < 4; ++c)
#pragma unroll
      for (int s = 0; s < 2; ++s) {
        const bf16x8 kf0 = *(const bf16x8*)(kt0 + (16 * s + col) * 256 +
                                            ((64 * c + 16 * q) ^ ksw));
        const bf16x8 kf1 = *(const bf16x8*)(kt1 + (16 * s + col) * 256 +
                                            ((64 * c + 16 * q) ^ ksw));
        st0[s] = __builtin_amdgcn_mfma_f32_16x16x32_bf16(kf0, qf[c], st0[s], 0, 0, 0);
        st1[s] = __builtin_amdgcn_mfma_f32_16x16x32_bf16(kf1, qf[c], st1[s], 0, 0, 0);
      }
    __builtin_amdgcn_s_setprio(0);

    // merged online softmax over all 16 scores (defer-max, threshold 8)
    float pmax = -1e30f;
#pragma unroll
    for (int s = 0; s < 2; ++s)
#pragma unroll
      for (int r = 0; r < 4; ++r) {
        pmax = fmaxf(pmax, st0[s][r]);
        pmax = fmaxf(pmax, st1[s][r]);
      }
    pmax = fmaxf(pmax, __shfl_xor(pmax, 16));
    pmax = fmaxf(pmax, __shfl_xor(pmax, 32));
    if (!__all(pmax - mrun <= 8.f)) {
      const float mnew = fmaxf(mrun, pmax);
      const float scl = __expf(mrun - mnew);
      mrun = mnew;
      lsum *= scl;
#pragma unroll
      for (int t = 0; t < 16; ++t) {
        ot[t][0] *= scl; ot[t][1] *= scl; ot[t][2] *= scl; ot[t][3] *= scl;
      }
    }
    float rsum = 0.f;
#pragma unroll
    for (int s = 0; s < 2; ++s)
#pragma unroll
      for (int r = 0; r < 4; ++r) {
        st0[s][r] = __expf(st0[s][r] - mrun);
        st1[s][r] = __expf(st1[s][r] - mrun);
        rsum += st0[s][r] + st1[s][r];
      }
    rsum += __shfl_xor(rsum, 16);
    rsum += __shfl_xor(rsum, 32);
    lsum += rsum;

    // P -> bf16 -> dual wave-private LDS regions -> B-fragments
    char* prow0 = plw0 + col * 128;
    char* prow1 = plw1 + col * 128;
#pragma unroll
    for (int s = 0; s < 2; ++s)
#pragma unroll
      for (int hp = 0; hp < 2; ++hp) {
        *(unsigned int*)(prow0 + ((32 * s + 8 * q + 4 * hp) ^ ksw)) =
            pk2(st0[s][2 * hp], st0[s][2 * hp + 1]);
        *(unsigned int*)(prow1 + ((32 * s + 8 * q + 4 * hp) ^ ksw)) =
            pk2(st1[s][2 * hp], st1[s][2 * hp + 1]);
      }
    const bf16x8 pf0 = *(const bf16x8*)(prow0 + ((16 * q) ^ ksw));
    const bf16x8 pf1 = *(const bf16x8*)(prow1 + ((16 * q) ^ ksw));

    // O^T += V^T . P^T  (iter0 = bytes 0..63 of pair, iter1 = bytes 64..127)
    __builtin_amdgcn_s_setprio(1);
#pragma unroll
    for (int t = 0; t < 16; ++t) {
      const int d = 16 * t + col;
      const int dsw = (d & 7) << 4;
      const bf16x8 vf0 = *(const bf16x8*)(vtc + d * 128 + ((16 * q) ^ dsw));
      ot[t] = __builtin_amdgcn_mfma_f32_16x16x32_bf16(vf0, pf0, ot[t], 0, 0, 0);
    }
#pragma unroll
    for (int t = 0; t < 16; ++t) {
      const int d = 16 * t + col;
      const int dsw = (d & 7) << 4;
      const bf16x8 vf1 = *(const bf16x8*)(vtc + d * 128 + ((64 + 16 * q) ^ dsw));
      ot[t] = __builtin_amdgcn_mfma_f32_16x16x32_bf16(vf1, pf1, ot[t], 0, 0, 0);
    }
    __builtin_amdgcn_s_setprio(0);

    __syncthreads();   // staged tiles complete + all waves done with cur bufs
  }

  // epilogue: y[b][gr][n][i] bf16. d = 16t+4q+r -> gr=r&1, i = 8t+2q+(r>>1)
  const float inv = 1.f / lsum;
  char* yt = lds;                    // [256 rows (gr*128+nl)][256B] swz (64KB)
  const int nl = 16 * w + col;
  const int swn = (nl & 7) << 4;
#pragma unroll
  for (int t = 0; t < 16; ++t) {
    const unsigned int w0 = pk2(ot[t][0] * inv, ot[t][2] * inv);
    const unsigned int w1 = pk2(ot[t][1] * inv, ot[t][3] * inv);
    const int bo = 16 * t + 4 * q;
    *(unsigned int*)(yt + nl * 256 + (bo ^ swn)) = w0;
    *(unsigned int*)(yt + (128 + nl) * 256 + (bo ^ swn)) = w1;
  }
  __syncthreads();
  {
    const int row = tid >> 1, h2 = tid & 1;
    const int gr = row >> 7, n = row & 127;
    unsigned short* dst = yB + (((size_t)(b * 2 + gr)) * 4096 + n0 + n) * 128 + h2 * 64;
    const char* srow = yt + row * 256;
    const int sw = (n & 7) << 4;
#pragma unroll
    for (int k = 0; k < 8; ++k)
      ((uint4*)dst)[k] = *(const uint4*)(srow + ((128 * h2 + 16 * k) ^ sw));
  }
}

// ---------------------------------------------------------------------------
// Final W conv (MFMA, K=128 per group) + bias + residual.
// ---------------------------------------------------------------------------
__global__ __launch_bounds__(256)
void k_final_mfma(const float* __restrict__ x,
                  const float* __restrict__ Ww, const float* __restrict__ Wb,
                  const float* __restrict__ ws, float* __restrict__ out) {
  const int nt = blockIdx.x, gq = blockIdx.y, b = blockIdx.z;
  const int gr = gq & 1, ob = (gq >> 1) * 128;
  const int n0 = nt * 128;
  const int tid = threadIdx.x;
  const int w = tid >> 6, lane = tid & 63, q = lane >> 4, col = lane & 15;
  const unsigned short* yb = (const unsigned short*)(ws + F_Y);

  __shared__ uint4 ldsb[4096];
  char* As = (char*)ldsb;
  char* Bs = (char*)ldsb + 16384;

  f32x4 acc[2][8];
#pragma unroll
  for (int h = 0; h < 2; ++h)
#pragma unroll
    for (int j = 0; j < 8; ++j) acc[h][j] = (f32x4){0.f, 0.f, 0.f, 0.f};

  const int ro = tid >> 1, haf = tid & 1;
  for (int ks = 0; ks < 2; ++ks) {
    __syncthreads();
    {
      const float* src = Ww + (size_t)(ob + ro) * 128 + ks * 64 + haf * 32;
      char* row = As + ro * 128;
      const int sw = (ro & 7) << 4;
#pragma unroll
      for (int jj = 0; jj < 4; ++jj) {
        float4 a = ((const float4*)src)[2 * jj];
        float4 c4 = ((const float4*)src)[2 * jj + 1];
        uint4 pk;
        pk.x = pk2(a.x, a.y);  pk.y = pk2(a.z, a.w);
        pk.z = pk2(c4.x, c4.y); pk.w = pk2(c4.z, c4.w);
        *(uint4*)(row + ((haf * 64 + 16 * jj) ^ sw)) = pk;
      }
    }
    {
      const unsigned short* src = yb + (((size_t)(b * 2 + gr)) * 4096 + n0 + ro) * 128 + ks * 64 + haf * 32;
      char* row = Bs + ro * 128;
      const int sw = (ro & 7) << 4;
#pragma unroll
      for (int jj = 0; jj < 4; ++jj)
        *(uint4*)(row + ((haf * 64 + 16 * jj) ^ sw)) = ((const uint4*)src)[jj];
    }
    __syncthreads();
#pragma unroll
    for (int c = 0; c < 2; ++c) {
      bf16x8 af[2], bfr[8];
#pragma unroll
      for (int h = 0; h < 2; ++h) {
        const int r = 32 * w + 16 * h + col;
        af[h] = *(const bf16x8*)(As + r * 128 + ((64 * c + 16 * q) ^ ((r & 7) << 4)));
      }
#pragma unroll
      for (int j = 0; j < 8; ++j) {
        const int r = 16 * j + col;
        bfr[j] = *(const bf16x8*)(Bs + r * 128 + ((64 * c + 16 * q) ^ ((r & 7) << 4)));
      }
#pragma unroll
      for (int h = 0; h < 2; ++h)
#pragma unroll
        for (int j = 0; j < 8; ++j)
          acc[h][j] = __builtin_amdgcn_mfma_f32_16x16x32_bf16(af[h], bfr[j], acc[h][j], 0, 0, 0);
    }
  }

  __syncthreads();                           // reuse whole LDS: f32 [128 o][512B]
  char* ft = (char*)ldsb;
#pragma unroll
  for (int h = 0; h < 2; ++h) {
    const int o0 = 32 * w + 16 * h + 4 * q;
#pragma unroll
    for (int j = 0; j < 8; ++j) {
      const int n = 16 * j + col;
#pragma unroll
      for (int r = 0; r < 4; ++r)
        *(float*)(ft + (o0 + r) * 512 + ((n * 4) ^ (((o0 + r) & 7) << 4))) = acc[h][j][r];
    }
  }
  __syncthreads();
  {
    const int o = tid >> 1, h2 = tid & 1;
    const float bsv = Wb[ob + o];
    const int ch = 2 * (ob + o) + gr;
    const size_t base = ((size_t)(b * 512 + ch)) * 4096 + n0 + h2 * 64;
    const char* row = ft + o * 512;
    const int sw = (o & 7) << 4;
#pragma unroll
    for (int k = 0; k < 16; ++k) {
      f32x4 v = *(const f32x4*)(row + ((256 * h2 + 16 * k) ^ sw));
      float4 xv = ((const float4*)(x + base))[k];
      ((float4*)(out + base))[k] = make_float4(v[0] + bsv + xv.x, v[1] + bsv + xv.y,
                                               v[2] + bsv + xv.z, v[3] + bsv + xv.w);
    }
  }
}

extern "C" void kernel_launch(void* const* d_in, const int* in_sizes, int n_in,
                              void* d_out, int out_size, void* d_ws, size_t ws_size,
                              hipStream_t stream) {
  const float* x  = (const float*)d_in[0];
  const float* gw = (const float*)d_in[1];
  const float* gb = (const float*)d_in[2];
  const float* tw = (const float*)d_in[3];
  const float* tb = (const float*)d_in[4];
  const float* pw = (const float*)d_in[5];
  const float* pb = (const float*)d_in[6];
  const float* Ww = (const float*)d_in[7];
  const float* Wb = (const float*)d_in[8];
  float* out = (float*)d_out;
  float* ws  = (float*)d_ws;

  k_prep<<<dim3(16, 8, 8), 256, 0, stream>>>(x, ws);
  k_proj_mfma<<<dim3(32, 2, 8), 256, 0, stream>>>(tw, tb, pw, pb, ws);
  k_g_mfma<<<dim3(32, 2, 8), 256, 0, stream>>>(gw, gb, ws);
  k_attn_mfma<<<dim3(8, 32), 512, 0, stream>>>(ws);
  k_final_mfma<<<dim3(32, 4, 8), 256, 0, stream>>>(x, Ww, Wb, ws, out);
}

// Round 14
// 124.516 us; speedup vs baseline: 1.6785x; 1.2579x over previous
//
#include <hip/hip_runtime.h>

// Workspace float offsets
#define F_Y     0u          // bf16 y[8][2][4096][128]    -> 4,194,304 f
#define F_TH    4194304u    // bf16 theta[8][4096][128]   -> 2,097,152 f
#define F_PHIB  6291456u    // bf16 phi[8][1024][128]     ->   524,288 f
#define F_GB    6815744u    // bf16 g[8][256][1024]       -> 1,048,576 f
// total 7,864,320 floats = 31.5 MB

typedef __attribute__((ext_vector_type(4))) float f32x4;
typedef __attribute__((ext_vector_type(8))) short bf16x8;

__device__ __forceinline__ unsigned short f2bf(float f) {
  union { unsigned int i; float f; } x; x.f = f;
  unsigned int r = x.i + 0x7fffu + ((x.i >> 16) & 1u);
  return (unsigned short)(r >> 16);
}
__device__ __forceinline__ unsigned int pk2(float a, float b) {
  return (unsigned int)f2bf(a) | ((unsigned int)f2bf(b) << 16);
}
__device__ __forceinline__ void gload_lds16(const void* g, void* l) {
  __builtin_amdgcn_global_load_lds(
      (const __attribute__((address_space(1))) unsigned int*)g,
      (__attribute__((address_space(3))) unsigned int*)l, 16, 0, 0);
}

// ---------------------------------------------------------------------------
// Fused front-end: x (f32 [b][512][4096]) -> theta[b][n][i] bf16,
// pooled phi[b][m][i] bf16, pooled g[b][d][m] bf16 — reads x exactly once.
// Per block: one 128-n tile, all 512 channels in 8 chunks of 64.
// 8 waves; each wave owns o-rows 16w..16w+15 of all 4 output tiles.
// X/W tiles [128][32c] bf16 in 80B-padded rows (2-way bank = free).
// ---------------------------------------------------------------------------
__global__ __launch_bounds__(512)
void k_front(const float* __restrict__ x,
             const float* __restrict__ tw, const float* __restrict__ tb,
             const float* __restrict__ pw, const float* __restrict__ pb,
             const float* __restrict__ gw, const float* __restrict__ gb,
             float* __restrict__ ws) {
  const int nt = blockIdx.x, b = blockIdx.y;
  const int n0 = nt * 128;
  const int tid = threadIdx.x;
  const int w = tid >> 6, lane = tid & 63, q = lane >> 4, col = lane & 15;

  __shared__ uint4 ldsb[5888];      // 94,208 B
  char* lds = (char*)ldsb;
  char* xs  = lds;                  // [64 ch][512B] f32, swz ((ch&7)<<4)
  char* Xm  = lds + 32768;          // [128 n][80B] bf16 (32 c)
  char* Xg0 = lds + 43008;
  char* Xg1 = lds + 53248;
  char* Wt  = lds + 63488;          // [128 o][80B]
  char* Wp  = lds + 73728;
  char* Wg  = lds + 83968;

  f32x4 at[8], ap[8], a0[8], a1[8];
#pragma unroll
  for (int j = 0; j < 8; ++j) {
    at[j] = (f32x4){0.f, 0.f, 0.f, 0.f};
    ap[j] = (f32x4){0.f, 0.f, 0.f, 0.f};
    a0[j] = (f32x4){0.f, 0.f, 0.f, 0.f};
    a1[j] = (f32x4){0.f, 0.f, 0.f, 0.f};
  }

  for (int kc = 0; kc < 8; ++kc) {
    // ---- A: stage x chunk (64 ch x 128 n f32) + 3 weight tiles ----
    {
      const int ch = tid >> 5;               // 0..15
      const int so = (tid & 31) * 16;        // byte within 512B row
#pragma unroll
      for (int i = 0; i < 4; ++i) {
        const int chh = 16 * i + ch;
        const float* src = x + ((size_t)(b * 512 + 64 * kc + chh)) * 4096 + n0;
        gload_lds16((const char*)src + (so ^ ((chh & 7) << 4)),
                    xs + 8192 * i + tid * 16);
      }
      const int o = tid >> 2, c4 = tid & 3;
      const size_t wo = (size_t)o * 256 + 32 * kc + 8 * c4;
      float4 t0 = ((const float4*)(tw + wo))[0], t1 = ((const float4*)(tw + wo))[1];
      float4 p0 = ((const float4*)(pw + wo))[0], p1 = ((const float4*)(pw + wo))[1];
      float4 g0 = ((const float4*)(gw + wo))[0], g1 = ((const float4*)(gw + wo))[1];
      *(uint4*)(Wt + o * 80 + 16 * c4) =
          make_uint4(pk2(t0.x, t0.y), pk2(t0.z, t0.w), pk2(t1.x, t1.y), pk2(t1.z, t1.w));
      *(uint4*)(Wp + o * 80 + 16 * c4) =
          make_uint4(pk2(p0.x, p0.y), pk2(p0.z, p0.w), pk2(p1.x, p1.y), pk2(p1.z, p1.w));
      *(uint4*)(Wg + o * 80 + 16 * c4) =
          make_uint4(pk2(g0.x, g0.y), pk2(g0.z, g0.w), pk2(g1.x, g1.y), pk2(g1.z, g1.w));
    }
    __syncthreads();
    // ---- B: pack X tiles (mean / group0 / group1) ----
    {
      const int n = tid >> 2, c4 = tid & 3;
      unsigned um[4], u0[4], u1[4];
#pragma unroll
      for (int s = 0; s < 4; ++s) {
        float v[4];
#pragma unroll
        for (int e = 0; e < 2; ++e) {
          const int cp = 8 * c4 + 2 * s + e;   // c' 0..31
          const int l0 = 2 * cp, l1 = 2 * cp + 1;
          v[2 * e]     = *(const float*)(xs + l0 * 512 + ((n * 4) ^ ((l0 & 7) << 4)));
          v[2 * e + 1] = *(const float*)(xs + l1 * 512 + ((n * 4) ^ ((l1 & 7) << 4)));
        }
        um[s] = pk2(0.5f * (v[0] + v[1]), 0.5f * (v[2] + v[3]));
        u0[s] = pk2(v[0], v[2]);
        u1[s] = pk2(v[1], v[3]);
      }
      *(uint4*)(Xm  + n * 80 + 16 * c4) = make_uint4(um[0], um[1], um[2], um[3]);
      *(uint4*)(Xg0 + n * 80 + 16 * c4) = make_uint4(u0[0], u0[1], u0[2], u0[3]);
      *(uint4*)(Xg1 + n * 80 + 16 * c4) = make_uint4(u1[0], u1[1], u1[2], u1[3]);
    }
    __syncthreads();
    // ---- C: MFMA (4 tiles x 8 j, K=32) ----
    {
      const int ar = 16 * w + col;
      const bf16x8 aft = *(const bf16x8*)(Wt + ar * 80 + 16 * q);
      const bf16x8 afp = *(const bf16x8*)(Wp + ar * 80 + 16 * q);
      const bf16x8 afg = *(const bf16x8*)(Wg + ar * 80 + 16 * q);
#pragma unroll
      for (int j = 0; j < 8; ++j) {
        const int br = 16 * j + col;
        const bf16x8 bm = *(const bf16x8*)(Xm  + br * 80 + 16 * q);
        const bf16x8 b0 = *(const bf16x8*)(Xg0 + br * 80 + 16 * q);
        const bf16x8 b1 = *(const bf16x8*)(Xg1 + br * 80 + 16 * q);
        at[j] = __builtin_amdgcn_mfma_f32_16x16x32_bf16(aft, bm, at[j], 0, 0, 0);
        ap[j] = __builtin_amdgcn_mfma_f32_16x16x32_bf16(afp, bm, ap[j], 0, 0, 0);
        a0[j] = __builtin_amdgcn_mfma_f32_16x16x32_bf16(afg, b0, a0[j], 0, 0, 0);
        a1[j] = __builtin_amdgcn_mfma_f32_16x16x32_bf16(afg, b1, a1[j], 0, 0, 0);
      }
    }
    __syncthreads();
  }

  const int o0 = 16 * w + 4 * q;
  const int mb = (nt >> 3) * 256 + (nt & 7) * 32;

  // theta -> trb (reuse xs region) with bias
  {
    float bst[4];
#pragma unroll
    for (int r = 0; r < 4; ++r) bst[r] = tb[o0 + r];
#pragma unroll
    for (int j = 0; j < 8; ++j) {
      const int n = 16 * j + col;
      uint2 pkk = make_uint2(pk2(at[j][0] + bst[0], at[j][1] + bst[1]),
                             pk2(at[j][2] + bst[2], at[j][3] + bst[3]));
      *(uint2*)(xs + n * 256 + ((2 * o0) ^ ((n & 7) << 4))) = pkk;
    }
  }

  // phi: fused (1,2,2) max-pool -> phiB[b][m][o] directly
  {
    float bsp[4];
#pragma unroll
    for (int r = 0; r < 4; ++r) bsp[r] = pb[o0 + r];
    unsigned short* phiB = (unsigned short*)(ws + F_PHIB);
#pragma unroll
    for (int jj = 0; jj < 4; ++jj) {
      const int j = (jj >> 1) * 4 + (jj & 1);   // {0,1,4,5}
      f32x4 pm;
#pragma unroll
      for (int r = 0; r < 4; ++r) pm[r] = fmaxf(ap[j][r], ap[j + 2][r]);
#pragma unroll
      for (int r = 0; r < 4; ++r) pm[r] = fmaxf(pm[r], __shfl_xor(pm[r], 1));
      if ((col & 1) == 0) {
        const int vp = 8 * (j & 1) + (col >> 1);
        const int m = mb + 16 * (j >> 2) + vp;
        uint2 pkk = make_uint2(pk2(pm[0] + bsp[0], pm[1] + bsp[1]),
                               pk2(pm[2] + bsp[2], pm[3] + bsp[3]));
        *(uint2*)(phiB + ((size_t)(b * 1024) + m) * 128 + o0) = pkk;
      }
    }
  }

  // g: fused pool into pt regions (reuse Xg0/Xg1), then coalesced copy
  {
    float bsg[4];
#pragma unroll
    for (int r = 0; r < 4; ++r) bsg[r] = gb[o0 + r];
#pragma unroll
    for (int gr = 0; gr < 2; ++gr) {
      char* pt = gr ? Xg1 : Xg0;
      const f32x4* ag = gr ? a1 : a0;
#pragma unroll
      for (int jj = 0; jj < 4; ++jj) {
        const int j = (jj >> 1) * 4 + (jj & 1);
        f32x4 pm;
#pragma unroll
        for (int r = 0; r < 4; ++r) pm[r] = fmaxf(ag[j][r], ag[j + 2][r]);
#pragma unroll
        for (int r = 0; r < 4; ++r) pm[r] = fmaxf(pm[r], __shfl_xor(pm[r], 1));
        if ((col & 1) == 0) {
          const int ml = 16 * (j >> 2) + 8 * (j & 1) + (col >> 1);
#pragma unroll
          for (int r = 0; r < 4; ++r)
            *(unsigned short*)(pt + (o0 + r) * 80 + ml * 2) = f2bf(pm[r] + bsg[r]);
        }
      }
    }
  }
  __syncthreads();

  // coalesced copies: theta [128 n][128 i], g [256 d][32 m]
  {
    const int n = tid >> 2, seg = tid & 3;
    unsigned short* dst = (unsigned short*)(ws + F_TH) +
                          ((size_t)(b * 4096) + n0 + n) * 128 + seg * 32;
    const char* row = xs + n * 256;
    const int sw = (n & 7) << 4;
#pragma unroll
    for (int k = 0; k < 4; ++k)
      ((uint4*)dst)[k] = *(const uint4*)(row + ((64 * seg + 16 * k) ^ sw));
  }
  if (tid < 256) {
    const int o = tid >> 1, gr = tid & 1;
    const char* row = (gr ? Xg1 : Xg0) + o * 80;
    unsigned short* dst = (unsigned short*)(ws + F_GB) +
                          ((size_t)(b * 256) + 2 * o + gr) * 1024 + mb;
#pragma unroll
    for (int k = 0; k < 4; ++k)
      ((uint4*)dst)[k] = *(const uint4*)(row + 16 * k);
  }
}

// ---------------------------------------------------------------------------
// MFMA flash attention (R13 structure): 2 iterations per barrier, K 4-buf,
// V pair-dbuf, merged softmax, dual wave-private P. LDS 128KB, 16 barriers.
// ---------------------------------------------------------------------------
#define NSIT 16
__global__ __launch_bounds__(512)
void k_attn_mfma(float* __restrict__ ws) {
  const int b = blockIdx.x;          // 8 batches -> 8 XCDs (round-robin)
  const int n0 = blockIdx.y * 128;
  const int tid = threadIdx.x;
  const int w = tid >> 6;
  const int lane = tid & 63;
  const int q = lane >> 4;
  const int col = lane & 15;
  const int ksw = (col & 7) << 4;

  __shared__ char lds[131072];
  char* plw0 = lds + 98304 + w * 4096;
  char* plw1 = plw0 + 2048;

  const unsigned short* thetaB = (const unsigned short*)(ws + F_TH);
  const char* phiBb = (const char*)((const unsigned short*)(ws + F_PHIB) + (size_t)b * 1024 * 128);
  const char* gBb   = (const char*)((const unsigned short*)(ws + F_GB) + (size_t)b * 256 * 1024);
  unsigned short* yB = (unsigned short*)(ws + F_Y);

  const int kr0 = lane >> 4;
  const int kso = (lane & 15) * 16;
  const int vr0 = lane >> 3;
  const int vso = (lane & 7) * 16;

  bf16x8 qf[4];
  {
    const unsigned short* qp = thetaB + ((size_t)(b * 4096 + n0 + 16 * w + col)) * 128 + 8 * q;
#pragma unroll
    for (int c = 0; c < 4; ++c) qf[c] = *(const bf16x8*)(qp + 32 * c);
  }

  f32x4 ot[16];
#pragma unroll
  for (int t = 0; t < 16; ++t) ot[t] = (f32x4){0.f, 0.f, 0.f, 0.f};
  float mrun = -1e30f, lsum = 0.f;

  {
    const int r = 4 * w + kr0;
    gload_lds16(phiBb + (size_t)r * 256 + (kso ^ ((r & 7) << 4)), lds + w * 1024);
    gload_lds16(phiBb + (size_t)(32 + r) * 256 + (kso ^ ((r & 7) << 4)),
                lds + 8192 + w * 1024);
#pragma unroll
    for (int j = 0; j < 4; ++j) {
      const int c = 4 * w + j;
      const int d = 8 * c + vr0;
      gload_lds16(gBb + (size_t)d * 2048 + (vso ^ ((d & 7) << 4)),
                  lds + 32768 + c * 1024);
    }
  }
  __syncthreads();

  for (int sit = 0; sit < NSIT; ++sit) {
    char* kt0 = lds + ((2 * sit) & 3) * 8192;
    char* kt1 = lds + ((2 * sit + 1) & 3) * 8192;
    char* vtc = lds + 32768 + (sit & 1) * 32768;

    if (sit + 1 < NSIT) {
      const int r = 4 * w + kr0;
      const int swk = (kso ^ ((r & 7) << 4));
      gload_lds16(phiBb + (size_t)((2 * sit + 2) * 32 + r) * 256 + swk,
                  lds + ((2 * sit + 2) & 3) * 8192 + w * 1024);
      gload_lds16(phiBb + (size_t)((2 * sit + 3) * 32 + r) * 256 + swk,
                  lds + ((2 * sit + 3) & 3) * 8192 + w * 1024);
      const size_t vm = (size_t)((sit + 1) * 64) * 2;
#pragma unroll
      for (int j = 0; j < 4; ++j) {
        const int c = 4 * w + j;
        const int d = 8 * c + vr0;
        gload_lds16(gBb + (size_t)d * 2048 + vm + (vso ^ ((d & 7) << 4)),
                    lds + 32768 + ((sit & 1) ^ 1) * 32768 + c * 1024);
      }
    }

    f32x4 st0[2], st1[2];
#pragma unroll
    for (int s = 0; s < 2; ++s) {
      st0[s] = (f32x4){0.f, 0.f, 0.f, 0.f};
      st1[s] = (f32x4){0.f, 0.f, 0.f, 0.f};
    }
    __builtin_amdgcn_s_setprio(1);
#pragma unroll
    for (int c = 0; c < 4; ++c)
#pragma unroll
      for (int s = 0; s < 2; ++s) {
        const bf16x8 kf0 = *(const bf16x8*)(kt0 + (16 * s + col) * 256 +
                                            ((64 * c + 16 * q) ^ ksw));
        const bf16x8 kf1 = *(const bf16x8*)(kt1 + (16 * s + col) * 256 +
                                            ((64 * c + 16 * q) ^ ksw));
        st0[s] = __builtin_amdgcn_mfma_f32_16x16x32_bf16(kf0, qf[c], st0[s], 0, 0, 0);
        st1[s] = __builtin_amdgcn_mfma_f32_16x16x32_bf16(kf1, qf[c], st1[s], 0, 0, 0);
      }
    __builtin_amdgcn_s_setprio(0);

    float pmax = -1e30f;
#pragma unroll
    for (int s = 0; s < 2; ++s)
#pragma unroll
      for (int r = 0; r < 4; ++r) {
        pmax = fmaxf(pmax, st0[s][r]);
        pmax = fmaxf(pmax, st1[s][r]);
      }
    pmax = fmaxf(pmax, __shfl_xor(pmax, 16));
    pmax = fmaxf(pmax, __shfl_xor(pmax, 32));
    if (!__all(pmax - mrun <= 8.f)) {
      const float mnew = fmaxf(mrun, pmax);
      const float scl = __expf(mrun - mnew);
      mrun = mnew;
      lsum *= scl;
#pragma unroll
      for (int t = 0; t < 16; ++t) {
        ot[t][0] *= scl; ot[t][1] *= scl; ot[t][2] *= scl; ot[t][3] *= scl;
      }
    }
    float rsum = 0.f;
#pragma unroll
    for (int s = 0; s < 2; ++s)
#pragma unroll
      for (int r = 0; r < 4; ++r) {
        st0[s][r] = __expf(st0[s][r] - mrun);
        st1[s][r] = __expf(st1[s][r] - mrun);
        rsum += st0[s][r] + st1[s][r];
      }
    rsum += __shfl_xor(rsum, 16);
    rsum += __shfl_xor(rsum, 32);
    lsum += rsum;

    char* prow0 = plw0 + col * 128;
    char* prow1 = plw1 + col * 128;
#pragma unroll
    for (int s = 0; s < 2; ++s)
#pragma unroll
      for (int hp = 0; hp < 2; ++hp) {
        *(unsigned int*)(prow0 + ((32 * s + 8 * q + 4 * hp) ^ ksw)) =
            pk2(st0[s][2 * hp], st0[s][2 * hp + 1]);
        *(unsigned int*)(prow1 + ((32 * s + 8 * q + 4 * hp) ^ ksw)) =
            pk2(st1[s][2 * hp], st1[s][2 * hp + 1]);
      }
    const bf16x8 pf0 = *(const bf16x8*)(prow0 + ((16 * q) ^ ksw));
    const bf16x8 pf1 = *(const bf16x8*)(prow1 + ((16 * q) ^ ksw));

    __builtin_amdgcn_s_setprio(1);
#pragma unroll
    for (int t = 0; t < 16; ++t) {
      const int d = 16 * t + col;
      const int dsw = (d & 7) << 4;
      const bf16x8 vf0 = *(const bf16x8*)(vtc + d * 128 + ((16 * q) ^ dsw));
      ot[t] = __builtin_amdgcn_mfma_f32_16x16x32_bf16(vf0, pf0, ot[t], 0, 0, 0);
    }
#pragma unroll
    for (int t = 0; t < 16; ++t) {
      const int d = 16 * t + col;
      const int dsw = (d & 7) << 4;
      const bf16x8 vf1 = *(const bf16x8*)(vtc + d * 128 + ((64 + 16 * q) ^ dsw));
      ot[t] = __builtin_amdgcn_mfma_f32_16x16x32_bf16(vf1, pf1, ot[t], 0, 0, 0);
    }
    __builtin_amdgcn_s_setprio(0);

    __syncthreads();
  }

  const float inv = 1.f / lsum;
  char* yt = lds;
  const int nl = 16 * w + col;
  const int swn = (nl & 7) << 4;
#pragma unroll
  for (int t = 0; t < 16; ++t) {
    const unsigned int w0 = pk2(ot[t][0] * inv, ot[t][2] * inv);
    const unsigned int w1 = pk2(ot[t][1] * inv, ot[t][3] * inv);
    const int bo = 16 * t + 4 * q;
    *(unsigned int*)(yt + nl * 256 + (bo ^ swn)) = w0;
    *(unsigned int*)(yt + (128 + nl) * 256 + (bo ^ swn)) = w1;
  }
  __syncthreads();
  {
    const int row = tid >> 1, h2 = tid & 1;
    const int gr = row >> 7, n = row & 127;
    unsigned short* dst = yB + (((size_t)(b * 2 + gr)) * 4096 + n0 + n) * 128 + h2 * 64;
    const char* srow = yt + row * 256;
    const int sw = (n & 7) << 4;
#pragma unroll
    for (int k = 0; k < 8; ++k)
      ((uint4*)dst)[k] = *(const uint4*)(srow + ((128 * h2 + 16 * k) ^ sw));
  }
}

// ---------------------------------------------------------------------------
// Final W conv (MFMA, K=128 per group) + bias + residual.
// ---------------------------------------------------------------------------
__global__ __launch_bounds__(256)
void k_final_mfma(const float* __restrict__ x,
                  const float* __restrict__ Ww, const float* __restrict__ Wb,
                  const float* __restrict__ ws, float* __restrict__ out) {
  const int nt = blockIdx.x, gq = blockIdx.y, b = blockIdx.z;
  const int gr = gq & 1, ob = (gq >> 1) * 128;
  const int n0 = nt * 128;
  const int tid = threadIdx.x;
  const int w = tid >> 6, lane = tid & 63, q = lane >> 4, col = lane & 15;
  const unsigned short* yb = (const unsigned short*)(ws + F_Y);

  __shared__ uint4 ldsb[4096];
  char* As = (char*)ldsb;
  char* Bs = (char*)ldsb + 16384;

  f32x4 acc[2][8];
#pragma unroll
  for (int h = 0; h < 2; ++h)
#pragma unroll
    for (int j = 0; j < 8; ++j) acc[h][j] = (f32x4){0.f, 0.f, 0.f, 0.f};

  const int ro = tid >> 1, haf = tid & 1;
  for (int ks = 0; ks < 2; ++ks) {
    __syncthreads();
    {
      const float* src = Ww + (size_t)(ob + ro) * 128 + ks * 64 + haf * 32;
      char* row = As + ro * 128;
      const int sw = (ro & 7) << 4;
#pragma unroll
      for (int jj = 0; jj < 4; ++jj) {
        float4 a = ((const float4*)src)[2 * jj];
        float4 c4 = ((const float4*)src)[2 * jj + 1];
        uint4 pk;
        pk.x = pk2(a.x, a.y);  pk.y = pk2(a.z, a.w);
        pk.z = pk2(c4.x, c4.y); pk.w = pk2(c4.z, c4.w);
        *(uint4*)(row + ((haf * 64 + 16 * jj) ^ sw)) = pk;
      }
    }
    {
      const unsigned short* src = yb + (((size_t)(b * 2 + gr)) * 4096 + n0 + ro) * 128 + ks * 64 + haf * 32;
      char* row = Bs + ro * 128;
      const int sw = (ro & 7) << 4;
#pragma unroll
      for (int jj = 0; jj < 4; ++jj)
        *(uint4*)(row + ((haf * 64 + 16 * jj) ^ sw)) = ((const uint4*)src)[jj];
    }
    __syncthreads();
#pragma unroll
    for (int c = 0; c < 2; ++c) {
      bf16x8 af[2], bfr[8];
#pragma unroll
      for (int h = 0; h < 2; ++h) {
        const int r = 32 * w + 16 * h + col;
        af[h] = *(const bf16x8*)(As + r * 128 + ((64 * c + 16 * q) ^ ((r & 7) << 4)));
      }
#pragma unroll
      for (int j = 0; j < 8; ++j) {
        const int r = 16 * j + col;
        bfr[j] = *(const bf16x8*)(Bs + r * 128 + ((64 * c + 16 * q) ^ ((r & 7) << 4)));
      }
#pragma unroll
      for (int h = 0; h < 2; ++h)
#pragma unroll
        for (int j = 0; j < 8; ++j)
          acc[h][j] = __builtin_amdgcn_mfma_f32_16x16x32_bf16(af[h], bfr[j], acc[h][j], 0, 0, 0);
    }
  }

  __syncthreads();                           // reuse whole LDS: f32 [128 o][512B]
  char* ft = (char*)ldsb;
#pragma unroll
  for (int h = 0; h < 2; ++h) {
    const int o0 = 32 * w + 16 * h + 4 * q;
#pragma unroll
    for (int j = 0; j < 8; ++j) {
      const int n = 16 * j + col;
#pragma unroll
      for (int r = 0; r < 4; ++r)
        *(float*)(ft + (o0 + r) * 512 + ((n * 4) ^ (((o0 + r) & 7) << 4))) = acc[h][j][r];
    }
  }
  __syncthreads();
  {
    const int o = tid >> 1, h2 = tid & 1;
    const float bsv = Wb[ob + o];
    const int ch = 2 * (ob + o) + gr;
    const size_t base = ((size_t)(b * 512 + ch)) * 4096 + n0 + h2 * 64;
    const char* row = ft + o * 512;
    const int sw = (o & 7) << 4;
#pragma unroll
    for (int k = 0; k < 16; ++k) {
      f32x4 v = *(const f32x4*)(row + ((256 * h2 + 16 * k) ^ sw));
      float4 xv = ((const float4*)(x + base))[k];
      ((float4*)(out + base))[k] = make_float4(v[0] + bsv + xv.x, v[1] + bsv + xv.y,
                                               v[2] + bsv + xv.z, v[3] + bsv + xv.w);
    }
  }
}

extern "C" void kernel_launch(void* const* d_in, const int* in_sizes, int n_in,
                              void* d_out, int out_size, void* d_ws, size_t ws_size,
                              hipStream_t stream) {
  const float* x  = (const float*)d_in[0];
  const float* gw = (const float*)d_in[1];
  const float* gb = (const float*)d_in[2];
  const float* tw = (const float*)d_in[3];
  const float* tb = (const float*)d_in[4];
  const float* pw = (const float*)d_in[5];
  const float* pb = (const float*)d_in[6];
  const float* Ww = (const float*)d_in[7];
  const float* Wb = (const float*)d_in[8];
  float* out = (float*)d_out;
  float* ws  = (float*)d_ws;

  k_front<<<dim3(32, 8), 512, 0, stream>>>(x, tw, tb, pw, pb, gw, gb, ws);
  k_attn_mfma<<<dim3(8, 32), 512, 0, stream>>>(ws);
  k_final_mfma<<<dim3(32, 4, 8), 256, 0, stream>>>(x, Ww, Wb, ws, out);
}

// Round 15
// 108.544 us; speedup vs baseline: 1.9255x; 1.1471x over previous
//
#include <hip/hip_runtime.h>

// Workspace float offsets
#define F_TH    0u          // bf16 theta[8][4096][128]   -> 2,097,152 f
#define F_PHIB  2097152u    // bf16 phi[8][1024][128]     ->   524,288 f
#define F_GB    2621440u    // bf16 g[8][256][1024]       -> 1,048,576 f
// total 3,670,016 floats = 14.7 MB

typedef __attribute__((ext_vector_type(4))) float f32x4;
typedef __attribute__((ext_vector_type(8))) short bf16x8;

__device__ __forceinline__ unsigned short f2bf(float f) {
  union { unsigned int i; float f; } x; x.f = f;
  unsigned int r = x.i + 0x7fffu + ((x.i >> 16) & 1u);
  return (unsigned short)(r >> 16);
}
__device__ __forceinline__ unsigned int pk2(float a, float b) {
  return (unsigned int)f2bf(a) | ((unsigned int)f2bf(b) << 16);
}
__device__ __forceinline__ void gload_lds16(const void* g, void* l) {
  __builtin_amdgcn_global_load_lds(
      (const __attribute__((address_space(1))) unsigned int*)g,
      (__attribute__((address_space(3))) unsigned int*)l, 16, 0, 0);
}

// ---------------------------------------------------------------------------
// Fused front-end: x (f32 [b][512][4096]) -> theta[b][n][i] bf16,
// pooled phi[b][m][i] bf16, pooled g[b][d][m] bf16 — reads x exactly once.
// (unchanged from R14)
// ---------------------------------------------------------------------------
__global__ __launch_bounds__(512)
void k_front(const float* __restrict__ x,
             const float* __restrict__ tw, const float* __restrict__ tb,
             const float* __restrict__ pw, const float* __restrict__ pb,
             const float* __restrict__ gw, const float* __restrict__ gb,
             float* __restrict__ ws) {
  const int nt = blockIdx.x, b = blockIdx.y;
  const int n0 = nt * 128;
  const int tid = threadIdx.x;
  const int w = tid >> 6, lane = tid & 63, q = lane >> 4, col = lane & 15;

  __shared__ uint4 ldsb[5888];      // 94,208 B
  char* lds = (char*)ldsb;
  char* xs  = lds;                  // [64 ch][512B] f32, swz ((ch&7)<<4)
  char* Xm  = lds + 32768;          // [128 n][80B] bf16 (32 c)
  char* Xg0 = lds + 43008;
  char* Xg1 = lds + 53248;
  char* Wt  = lds + 63488;          // [128 o][80B]
  char* Wp  = lds + 73728;
  char* Wg  = lds + 83968;

  f32x4 at[8], ap[8], a0[8], a1[8];
#pragma unroll
  for (int j = 0; j < 8; ++j) {
    at[j] = (f32x4){0.f, 0.f, 0.f, 0.f};
    ap[j] = (f32x4){0.f, 0.f, 0.f, 0.f};
    a0[j] = (f32x4){0.f, 0.f, 0.f, 0.f};
    a1[j] = (f32x4){0.f, 0.f, 0.f, 0.f};
  }

  for (int kc = 0; kc < 8; ++kc) {
    {
      const int ch = tid >> 5;               // 0..15
      const int so = (tid & 31) * 16;        // byte within 512B row
#pragma unroll
      for (int i = 0; i < 4; ++i) {
        const int chh = 16 * i + ch;
        const float* src = x + ((size_t)(b * 512 + 64 * kc + chh)) * 4096 + n0;
        gload_lds16((const char*)src + (so ^ ((chh & 7) << 4)),
                    xs + 8192 * i + tid * 16);
      }
      const int o = tid >> 2, c4 = tid & 3;
      const size_t wo = (size_t)o * 256 + 32 * kc + 8 * c4;
      float4 t0 = ((const float4*)(tw + wo))[0], t1 = ((const float4*)(tw + wo))[1];
      float4 p0 = ((const float4*)(pw + wo))[0], p1 = ((const float4*)(pw + wo))[1];
      float4 g0 = ((const float4*)(gw + wo))[0], g1 = ((const float4*)(gw + wo))[1];
      *(uint4*)(Wt + o * 80 + 16 * c4) =
          make_uint4(pk2(t0.x, t0.y), pk2(t0.z, t0.w), pk2(t1.x, t1.y), pk2(t1.z, t1.w));
      *(uint4*)(Wp + o * 80 + 16 * c4) =
          make_uint4(pk2(p0.x, p0.y), pk2(p0.z, p0.w), pk2(p1.x, p1.y), pk2(p1.z, p1.w));
      *(uint4*)(Wg + o * 80 + 16 * c4) =
          make_uint4(pk2(g0.x, g0.y), pk2(g0.z, g0.w), pk2(g1.x, g1.y), pk2(g1.z, g1.w));
    }
    __syncthreads();
    {
      const int n = tid >> 2, c4 = tid & 3;
      unsigned um[4], u0[4], u1[4];
#pragma unroll
      for (int s = 0; s < 4; ++s) {
        float v[4];
#pragma unroll
        for (int e = 0; e < 2; ++e) {
          const int cp = 8 * c4 + 2 * s + e;   // c' 0..31
          const int l0 = 2 * cp, l1 = 2 * cp + 1;
          v[2 * e]     = *(const float*)(xs + l0 * 512 + ((n * 4) ^ ((l0 & 7) << 4)));
          v[2 * e + 1] = *(const float*)(xs + l1 * 512 + ((n * 4) ^ ((l1 & 7) << 4)));
        }
        um[s] = pk2(0.5f * (v[0] + v[1]), 0.5f * (v[2] + v[3]));
        u0[s] = pk2(v[0], v[2]);
        u1[s] = pk2(v[1], v[3]);
      }
      *(uint4*)(Xm  + n * 80 + 16 * c4) = make_uint4(um[0], um[1], um[2], um[3]);
      *(uint4*)(Xg0 + n * 80 + 16 * c4) = make_uint4(u0[0], u0[1], u0[2], u0[3]);
      *(uint4*)(Xg1 + n * 80 + 16 * c4) = make_uint4(u1[0], u1[1], u1[2], u1[3]);
    }
    __syncthreads();
    {
      const int ar = 16 * w + col;
      const bf16x8 aft = *(const bf16x8*)(Wt + ar * 80 + 16 * q);
      const bf16x8 afp = *(const bf16x8*)(Wp + ar * 80 + 16 * q);
      const bf16x8 afg = *(const bf16x8*)(Wg + ar * 80 + 16 * q);
#pragma unroll
      for (int j = 0; j < 8; ++j) {
        const int br = 16 * j + col;
        const bf16x8 bm = *(const bf16x8*)(Xm  + br * 80 + 16 * q);
        const bf16x8 b0 = *(const bf16x8*)(Xg0 + br * 80 + 16 * q);
        const bf16x8 b1 = *(const bf16x8*)(Xg1 + br * 80 + 16 * q);
        at[j] = __builtin_amdgcn_mfma_f32_16x16x32_bf16(aft, bm, at[j], 0, 0, 0);
        ap[j] = __builtin_amdgcn_mfma_f32_16x16x32_bf16(afp, bm, ap[j], 0, 0, 0);
        a0[j] = __builtin_amdgcn_mfma_f32_16x16x32_bf16(afg, b0, a0[j], 0, 0, 0);
        a1[j] = __builtin_amdgcn_mfma_f32_16x16x32_bf16(afg, b1, a1[j], 0, 0, 0);
      }
    }
    __syncthreads();
  }

  const int o0 = 16 * w + 4 * q;
  const int mb = (nt >> 3) * 256 + (nt & 7) * 32;

  {
    float bst[4];
#pragma unroll
    for (int r = 0; r < 4; ++r) bst[r] = tb[o0 + r];
#pragma unroll
    for (int j = 0; j < 8; ++j) {
      const int n = 16 * j + col;
      uint2 pkk = make_uint2(pk2(at[j][0] + bst[0], at[j][1] + bst[1]),
                             pk2(at[j][2] + bst[2], at[j][3] + bst[3]));
      *(uint2*)(xs + n * 256 + ((2 * o0) ^ ((n & 7) << 4))) = pkk;
    }
  }

  {
    float bsp[4];
#pragma unroll
    for (int r = 0; r < 4; ++r) bsp[r] = pb[o0 + r];
    unsigned short* phiB = (unsigned short*)(ws + F_PHIB);
#pragma unroll
    for (int jj = 0; jj < 4; ++jj) {
      const int j = (jj >> 1) * 4 + (jj & 1);   // {0,1,4,5}
      f32x4 pm;
#pragma unroll
      for (int r = 0; r < 4; ++r) pm[r] = fmaxf(ap[j][r], ap[j + 2][r]);
#pragma unroll
      for (int r = 0; r < 4; ++r) pm[r] = fmaxf(pm[r], __shfl_xor(pm[r], 1));
      if ((col & 1) == 0) {
        const int vp = 8 * (j & 1) + (col >> 1);
        const int m = mb + 16 * (j >> 2) + vp;
        uint2 pkk = make_uint2(pk2(pm[0] + bsp[0], pm[1] + bsp[1]),
                               pk2(pm[2] + bsp[2], pm[3] + bsp[3]));
        *(uint2*)(phiB + ((size_t)(b * 1024) + m) * 128 + o0) = pkk;
      }
    }
  }

  {
    float bsg[4];
#pragma unroll
    for (int r = 0; r < 4; ++r) bsg[r] = gb[o0 + r];
#pragma unroll
    for (int gr = 0; gr < 2; ++gr) {
      char* pt = gr ? Xg1 : Xg0;
      const f32x4* ag = gr ? a1 : a0;
#pragma unroll
      for (int jj = 0; jj < 4; ++jj) {
        const int j = (jj >> 1) * 4 + (jj & 1);
        f32x4 pm;
#pragma unroll
        for (int r = 0; r < 4; ++r) pm[r] = fmaxf(ag[j][r], ag[j + 2][r]);
#pragma unroll
        for (int r = 0; r < 4; ++r) pm[r] = fmaxf(pm[r], __shfl_xor(pm[r], 1));
        if ((col & 1) == 0) {
          const int ml = 16 * (j >> 2) + 8 * (j & 1) + (col >> 1);
#pragma unroll
          for (int r = 0; r < 4; ++r)
            *(unsigned short*)(pt + (o0 + r) * 80 + ml * 2) = f2bf(pm[r] + bsg[r]);
        }
      }
    }
  }
  __syncthreads();

  {
    const int n = tid >> 2, seg = tid & 3;
    unsigned short* dst = (unsigned short*)(ws + F_TH) +
                          ((size_t)(b * 4096) + n0 + n) * 128 + seg * 32;
    const char* row = xs + n * 256;
    const int sw = (n & 7) << 4;
#pragma unroll
    for (int k = 0; k < 4; ++k)
      ((uint4*)dst)[k] = *(const uint4*)(row + ((64 * seg + 16 * k) ^ sw));
  }
  if (tid < 256) {
    const int o = tid >> 1, gr = tid & 1;
    const char* row = (gr ? Xg1 : Xg0) + o * 80;
    unsigned short* dst = (unsigned short*)(ws + F_GB) +
                          ((size_t)(b * 256) + 2 * o + gr) * 1024 + mb;
#pragma unroll
    for (int k = 0; k < 4; ++k)
      ((uint4*)dst)[k] = *(const uint4*)(row + 16 * k);
  }
}

// ---------------------------------------------------------------------------
// MFMA flash attention (R13 main loop) + FUSED final W conv + bias + residual.
// After the attn loop, y (bf16) sits in LDS in exact B-fragment layout;
// each wave computes o-rows 32w..32w+31 x both groups (128 MFMA/wave) with
// W A-fragments packed in-register from global (L2-resident), then a per-group
// f32 LDS transpose emits coalesced out = Wy + Wb + x. No y HBM round-trip.
// ---------------------------------------------------------------------------
#define NSIT 16
__global__ __launch_bounds__(512)
void k_attn_mfma(const float* __restrict__ x,
                 const float* __restrict__ Ww, const float* __restrict__ Wb,
                 float* __restrict__ ws, float* __restrict__ out) {
  const int b = blockIdx.x;          // 8 batches -> 8 XCDs (round-robin)
  const int n0 = blockIdx.y * 128;
  const int tid = threadIdx.x;
  const int w = tid >> 6;
  const int lane = tid & 63;
  const int q = lane >> 4;
  const int col = lane & 15;
  const int ksw = (col & 7) << 4;

  __shared__ char lds[131072];
  char* plw0 = lds + 98304 + w * 4096;
  char* plw1 = plw0 + 2048;

  const unsigned short* thetaB = (const unsigned short*)(ws + F_TH);
  const char* phiBb = (const char*)((const unsigned short*)(ws + F_PHIB) + (size_t)b * 1024 * 128);
  const char* gBb   = (const char*)((const unsigned short*)(ws + F_GB) + (size_t)b * 256 * 1024);

  const int kr0 = lane >> 4;
  const int kso = (lane & 15) * 16;
  const int vr0 = lane >> 3;
  const int vso = (lane & 7) * 16;

  bf16x8 qf[4];
  {
    const unsigned short* qp = thetaB + ((size_t)(b * 4096 + n0 + 16 * w + col)) * 128 + 8 * q;
#pragma unroll
    for (int c = 0; c < 4; ++c) qf[c] = *(const bf16x8*)(qp + 32 * c);
  }

  f32x4 ot[16];
#pragma unroll
  for (int t = 0; t < 16; ++t) ot[t] = (f32x4){0.f, 0.f, 0.f, 0.f};
  float mrun = -1e30f, lsum = 0.f;

  {
    const int r = 4 * w + kr0;
    gload_lds16(phiBb + (size_t)r * 256 + (kso ^ ((r & 7) << 4)), lds + w * 1024);
    gload_lds16(phiBb + (size_t)(32 + r) * 256 + (kso ^ ((r & 7) << 4)),
                lds + 8192 + w * 1024);
#pragma unroll
    for (int j = 0; j < 4; ++j) {
      const int c = 4 * w + j;
      const int d = 8 * c + vr0;
      gload_lds16(gBb + (size_t)d * 2048 + (vso ^ ((d & 7) << 4)),
                  lds + 32768 + c * 1024);
    }
  }
  __syncthreads();

  for (int sit = 0; sit < NSIT; ++sit) {
    char* kt0 = lds + ((2 * sit) & 3) * 8192;
    char* kt1 = lds + ((2 * sit + 1) & 3) * 8192;
    char* vtc = lds + 32768 + (sit & 1) * 32768;

    if (sit + 1 < NSIT) {
      const int r = 4 * w + kr0;
      const int swk = (kso ^ ((r & 7) << 4));
      gload_lds16(phiBb + (size_t)((2 * sit + 2) * 32 + r) * 256 + swk,
                  lds + ((2 * sit + 2) & 3) * 8192 + w * 1024);
      gload_lds16(phiBb + (size_t)((2 * sit + 3) * 32 + r) * 256 + swk,
                  lds + ((2 * sit + 3) & 3) * 8192 + w * 1024);
      const size_t vm = (size_t)((sit + 1) * 64) * 2;
#pragma unroll
      for (int j = 0; j < 4; ++j) {
        const int c = 4 * w + j;
        const int d = 8 * c + vr0;
        gload_lds16(gBb + (size_t)d * 2048 + vm + (vso ^ ((d & 7) << 4)),
                    lds + 32768 + ((sit & 1) ^ 1) * 32768 + c * 1024);
      }
    }

    f32x4 st0[2], st1[2];
#pragma unroll
    for (int s = 0; s < 2; ++s) {
      st0[s] = (f32x4){0.f, 0.f, 0.f, 0.f};
      st1[s] = (f32x4){0.f, 0.f, 0.f, 0.f};
    }
    __builtin_amdgcn_s_setprio(1);
#pragma unroll
    for (int c = 0; c < 4; ++c)
#pragma unroll
      for (int s = 0; s < 2; ++s) {
        const bf16x8 kf0 = *(const bf16x8*)(kt0 + (16 * s + col) * 256 +
                                            ((64 * c + 16 * q) ^ ksw));
        const bf16x8 kf1 = *(const bf16x8*)(kt1 + (16 * s + col) * 256 +
                                            ((64 * c + 16 * q) ^ ksw));
        st0[s] = __builtin_amdgcn_mfma_f32_16x16x32_bf16(kf0, qf[c], st0[s], 0, 0, 0);
        st1[s] = __builtin_amdgcn_mfma_f32_16x16x32_bf16(kf1, qf[c], st1[s], 0, 0, 0);
      }
    __builtin_amdgcn_s_setprio(0);

    float pmax = -1e30f;
#pragma unroll
    for (int s = 0; s < 2; ++s)
#pragma unroll
      for (int r = 0; r < 4; ++r) {
        pmax = fmaxf(pmax, st0[s][r]);
        pmax = fmaxf(pmax, st1[s][r]);
      }
    pmax = fmaxf(pmax, __shfl_xor(pmax, 16));
    pmax = fmaxf(pmax, __shfl_xor(pmax, 32));
    if (!__all(pmax - mrun <= 8.f)) {
      const float mnew = fmaxf(mrun, pmax);
      const float scl = __expf(mrun - mnew);
      mrun = mnew;
      lsum *= scl;
#pragma unroll
      for (int t = 0; t < 16; ++t) {
        ot[t][0] *= scl; ot[t][1] *= scl; ot[t][2] *= scl; ot[t][3] *= scl;
      }
    }
    float rsum = 0.f;
#pragma unroll
    for (int s = 0; s < 2; ++s)
#pragma unroll
      for (int r = 0; r < 4; ++r) {
        st0[s][r] = __expf(st0[s][r] - mrun);
        st1[s][r] = __expf(st1[s][r] - mrun);
        rsum += st0[s][r] + st1[s][r];
      }
    rsum += __shfl_xor(rsum, 16);
    rsum += __shfl_xor(rsum, 32);
    lsum += rsum;

    char* prow0 = plw0 + col * 128;
    char* prow1 = plw1 + col * 128;
#pragma unroll
    for (int s = 0; s < 2; ++s)
#pragma unroll
      for (int hp = 0; hp < 2; ++hp) {
        *(unsigned int*)(prow0 + ((32 * s + 8 * q + 4 * hp) ^ ksw)) =
            pk2(st0[s][2 * hp], st0[s][2 * hp + 1]);
        *(unsigned int*)(prow1 + ((32 * s + 8 * q + 4 * hp) ^ ksw)) =
            pk2(st1[s][2 * hp], st1[s][2 * hp + 1]);
      }
    const bf16x8 pf0 = *(const bf16x8*)(prow0 + ((16 * q) ^ ksw));
    const bf16x8 pf1 = *(const bf16x8*)(prow1 + ((16 * q) ^ ksw));

    __builtin_amdgcn_s_setprio(1);
#pragma unroll
    for (int t = 0; t < 16; ++t) {
      const int d = 16 * t + col;
      const int dsw = (d & 7) << 4;
      const bf16x8 vf0 = *(const bf16x8*)(vtc + d * 128 + ((16 * q) ^ dsw));
      ot[t] = __builtin_amdgcn_mfma_f32_16x16x32_bf16(vf0, pf0, ot[t], 0, 0, 0);
    }
#pragma unroll
    for (int t = 0; t < 16; ++t) {
      const int d = 16 * t + col;
      const int dsw = (d & 7) << 4;
      const bf16x8 vf1 = *(const bf16x8*)(vtc + d * 128 + ((64 + 16 * q) ^ dsw));
      ot[t] = __builtin_amdgcn_mfma_f32_16x16x32_bf16(vf1, pf1, ot[t], 0, 0, 0);
    }
    __builtin_amdgcn_s_setprio(0);

    __syncthreads();
  }

  // ---- write normalized y tile to LDS (B-fragment layout) ----
  // yt rows: gr*128 + nl (nl = n-local), 256B per row (128 i bf16), swz ksw.
  const float inv = 1.f / lsum;
  char* yt = lds;
  {
    const int nl = 16 * w + col;
    const int swn = (nl & 7) << 4;
#pragma unroll
    for (int t = 0; t < 16; ++t) {
      const unsigned int w0 = pk2(ot[t][0] * inv, ot[t][2] * inv);
      const unsigned int w1 = pk2(ot[t][1] * inv, ot[t][3] * inv);
      const int bo = 16 * t + 4 * q;
      *(unsigned int*)(yt + nl * 256 + (bo ^ swn)) = w0;
      *(unsigned int*)(yt + (128 + nl) * 256 + (bo ^ swn)) = w1;
    }
  }
  __syncthreads();

  // ---- fused W conv: facc[gr][h][j] = sum_i Ww[32w+16h+col][i] * y[gr][n][i]
  f32x4 facc[2][2][8];
#pragma unroll
  for (int gr = 0; gr < 2; ++gr)
#pragma unroll
    for (int h = 0; h < 2; ++h)
#pragma unroll
      for (int j = 0; j < 8; ++j) facc[gr][h][j] = (f32x4){0.f, 0.f, 0.f, 0.f};

#pragma unroll
  for (int gr = 0; gr < 2; ++gr) {
#pragma unroll
    for (int c = 0; c < 4; ++c) {
      bf16x8 bfr[8];
#pragma unroll
      for (int j = 0; j < 8; ++j) {
        const int nl = 16 * j + col;
        bfr[j] = *(const bf16x8*)(yt + (128 * gr + nl) * 256 + ((64 * c + 16 * q) ^ ksw));
      }
#pragma unroll
      for (int h = 0; h < 2; ++h) {
        const int o = 32 * w + 16 * h + col;
        const float* wp = Ww + (size_t)o * 128 + 32 * c + 8 * q;
        const float4 w0 = ((const float4*)wp)[0];
        const float4 w1 = ((const float4*)wp)[1];
        union { unsigned u[4]; bf16x8 v; } af;
        af.u[0] = pk2(w0.x, w0.y); af.u[1] = pk2(w0.z, w0.w);
        af.u[2] = pk2(w1.x, w1.y); af.u[3] = pk2(w1.z, w1.w);
#pragma unroll
        for (int j = 0; j < 8; ++j)
          facc[gr][h][j] = __builtin_amdgcn_mfma_f32_16x16x32_bf16(af.v, bfr[j], facc[gr][h][j], 0, 0, 0);
      }
    }
  }
  __syncthreads();   // all waves done reading yt; LDS free for f32 transpose

  // ---- per-group f32 transpose + bias + residual + coalesced store ----
  char* ft = lds;    // [256 o][512B], swz ((o&7)<<4)  = 128KB
#pragma unroll
  for (int gr = 0; gr < 2; ++gr) {
#pragma unroll
    for (int h = 0; h < 2; ++h) {
      const int o0 = 32 * w + 16 * h + 4 * q;
#pragma unroll
      for (int j = 0; j < 8; ++j) {
        const int n = 16 * j + col;
#pragma unroll
        for (int r = 0; r < 4; ++r)
          *(float*)(ft + (o0 + r) * 512 + ((n * 4) ^ (((o0 + r) & 7) << 4))) =
              facc[gr][h][j][r];
      }
    }
    __syncthreads();
    {
      const int o = tid >> 1, h2 = tid & 1;
      const float bsv = Wb[o];
      const int ch = 2 * o + gr;
      const size_t base = ((size_t)(b * 512 + ch)) * 4096 + n0 + h2 * 64;
      const char* row = ft + o * 512;
      const int sw = (o & 7) << 4;
#pragma unroll
      for (int k = 0; k < 16; ++k) {
        f32x4 v = *(const f32x4*)(row + ((256 * h2 + 16 * k) ^ sw));
        float4 xv = ((const float4*)(x + base))[k];
        ((float4*)(out + base))[k] = make_float4(v[0] + bsv + xv.x, v[1] + bsv + xv.y,
                                                 v[2] + bsv + xv.z, v[3] + bsv + xv.w);
      }
    }
    if (gr == 0) __syncthreads();
  }
}

extern "C" void kernel_launch(void* const* d_in, const int* in_sizes, int n_in,
                              void* d_out, int out_size, void* d_ws, size_t ws_size,
                              hipStream_t stream) {
  const float* x  = (const float*)d_in[0];
  const float* gw = (const float*)d_in[1];
  const float* gb = (const float*)d_in[2];
  const float* tw = (const float*)d_in[3];
  const float* tb = (const float*)d_in[4];
  const float* pw = (const float*)d_in[5];
  const float* pb = (const float*)d_in[6];
  const float* Ww = (const float*)d_in[7];
  const float* Wb = (const float*)d_in[8];
  float* out = (float*)d_out;
  float* ws  = (float*)d_ws;

  k_front<<<dim3(32, 8), 512, 0, stream>>>(x, tw, tb, pw, pb, gw, gb, ws);
  k_attn_mfma<<<dim3(8, 32), 512, 0, stream>>>(x, Ww, Wb, ws, out);
}